// Round 7
// baseline (2324.114 us; speedup 1.0000x reference)
//
#include <hip/hip_runtime.h>
#include <hip/hip_bf16.h>
#include <math.h>

#define B_ 4
#define T_ 1024
#define D_ 1024
#define H_ 16
#define DH_ 64
#define M_ 4096
#define QSTR_ 3072   // fused qkv row stride
#define EPS_ 1e-5f

typedef __attribute__((ext_vector_type(4))) float f32x4;
typedef __attribute__((ext_vector_type(8))) short s16x8;

#if __has_builtin(__builtin_amdgcn_exp2f)
#define EXP2F __builtin_amdgcn_exp2f
#else
#define EXP2F exp2f
#endif

__device__ __forceinline__ float gelu_f(float x) {
  return 0.5f * x * (1.0f + erff(x * 0.70710678118654752f));
}
__device__ __forceinline__ float b2f(unsigned short u) {
  union { unsigned int i; float f; } c; c.i = ((unsigned int)u) << 16; return c.f;
}
__device__ __forceinline__ unsigned short f2b(float f) {
  __hip_bfloat16 h = __float2bfloat16(f);
  return *reinterpret_cast<unsigned short*>(&h);
}
__device__ __forceinline__ void g2l16(void* l, const void* g) {
  __builtin_amdgcn_global_load_lds(
      (const __attribute__((address_space(1))) void*)g,
      (__attribute__((address_space(3))) void*)l, 16, 0, 0);
}

// ---------------- LayerNorm ----------------
template<bool BF16OUT>
__global__ __launch_bounds__(256) void ln_kernel(
    const float* __restrict__ in, void* __restrict__ out,
    const float* __restrict__ g, const float* __restrict__ b) {
  const int row = blockIdx.x;
  const int tid = threadIdx.x;
  const float* rp = in + (size_t)row * D_;
  float4 v = *reinterpret_cast<const float4*>(rp + tid * 4);
  float s = v.x + v.y + v.z + v.w;
  float s2 = v.x * v.x + v.y * v.y + v.z * v.z + v.w * v.w;
#pragma unroll
  for (int off = 1; off < 64; off <<= 1) {
    s += __shfl_xor(s, off);
    s2 += __shfl_xor(s2, off);
  }
  __shared__ float red[2][4];
  const int wid = tid >> 6;
  if ((tid & 63) == 0) { red[0][wid] = s; red[1][wid] = s2; }
  __syncthreads();
  s = red[0][0] + red[0][1] + red[0][2] + red[0][3];
  s2 = red[1][0] + red[1][1] + red[1][2] + red[1][3];
  const float mu = s * (1.0f / D_);
  const float var = s2 * (1.0f / D_) - mu * mu;
  const float rs = rsqrtf(var + EPS_);
  float4 gv = *reinterpret_cast<const float4*>(g + tid * 4);
  float4 bv = *reinterpret_cast<const float4*>(b + tid * 4);
  float o0 = (v.x - mu) * rs * gv.x + bv.x;
  float o1 = (v.y - mu) * rs * gv.y + bv.y;
  float o2 = (v.z - mu) * rs * gv.z + bv.z;
  float o3 = (v.w - mu) * rs * gv.w + bv.w;
  if (BF16OUT) {
    ushort4 pk;
    pk.x = f2b(o0); pk.y = f2b(o1); pk.z = f2b(o2); pk.w = f2b(o3);
    *reinterpret_cast<ushort4*>((unsigned short*)out + (size_t)row * D_ + tid * 4) = pk;
  } else {
    *reinterpret_cast<float4*>((float*)out + (size_t)row * D_ + tid * 4) =
        make_float4(o0, o1, o2, o3);
  }
}

// ---------------- bias concat: [L][3072] <- bq|bk|bv ----------------
__global__ __launch_bounds__(256) void concat_bias(
    const float* __restrict__ bq, const float* __restrict__ bk,
    const float* __restrict__ bv, float* __restrict__ out) {
  const int i = blockIdx.x * 256 + threadIdx.x;
  const int l = i / QSTR_, c = i % QSTR_;
  const float* src = (c < 1024) ? bq : ((c < 2048) ? bk : bv);
  out[i] = src[l * 1024 + (c & 1023)];
}

// ---------------- all weight transposes for one layer, single launch ----------------
__device__ __forceinline__ void transpose_tile(
    const float* __restrict__ src, int sld,
    __hip_bfloat16* __restrict__ dst, int dld, int k0, int n0) {
  __shared__ float tile[32][33];
  const int t = threadIdx.x;
  const int r = t >> 3;
  const int cq = (t & 7) * 4;
  float4 vv = *reinterpret_cast<const float4*>(src + (size_t)(k0 + r) * sld + n0 + cq);
  tile[r][cq + 0] = vv.x; tile[r][cq + 1] = vv.y;
  tile[r][cq + 2] = vv.z; tile[r][cq + 3] = vv.w;
  __syncthreads();
  ushort4 o;
  o.x = f2b(tile[cq + 0][r]); o.y = f2b(tile[cq + 1][r]);
  o.z = f2b(tile[cq + 2][r]); o.w = f2b(tile[cq + 3][r]);
  *reinterpret_cast<ushort4*>((unsigned short*)dst + (size_t)(n0 + r) * dld + k0 + cq) = o;
}

struct TrAll {
  const float *wq, *wk, *wv, *wp, *w1, *w2;
  __hip_bfloat16 *dqkv, *dp, *d1, *d2;
};

__global__ __launch_bounds__(256) void transpose_all(TrAll a) {
  const int t = blockIdx.x;
  const float* src;
  __hip_bfloat16* dst;
  int sld, dld, k0, n0;
  if (t < 4096) {
    const int m = t >> 10, tile = t & 1023;
    k0 = (tile >> 5) * 32; n0 = (tile & 31) * 32;
    src = (m == 0) ? a.wq : (m == 1) ? a.wk : (m == 2) ? a.wv : a.wp;
    sld = 1024; dld = 1024;
    dst = (m < 3) ? (a.dqkv + (size_t)m * 1024 * 1024) : a.dp;
  } else if (t < 8192) {
    const int tile = t - 4096;
    k0 = (tile & 31) * 32; n0 = (tile >> 5) * 32;
    src = a.w1; sld = 4096; dst = a.d1; dld = 1024;
  } else {
    const int tile = t - 8192;
    k0 = (tile >> 5) * 32; n0 = (tile & 31) * 32;
    src = a.w2; sld = 1024; dst = a.d2; dld = 4096;
  }
  transpose_tile(src, sld, dst, dld, k0, n0);
}

// ---------------- bf16 MFMA GEMM: 3-deep pipeline, counted vmcnt, XCD swizzle -----
// C[128xBN tile] = A[M,K] @ Bt[N,K]^T + bias.  BN in {128, 64}.
// Tile t staged into buf t%3 at iteration t-2; per iter: counted vmcnt (never 0
// in steady state) + raw barriers keep 2 tiles of loads in flight across barriers.
// MODE 0: store bf16; MODE 1: fp32 C += result; MODE 2: store bf16 gelu(result)
template<int MODE, int BN>
__global__ __launch_bounds__(256) void gemm_mfma(
    const __hip_bfloat16* __restrict__ A,
    const __hip_bfloat16* __restrict__ Bt,
    const float* __restrict__ bias,
    void* __restrict__ Cout, int N, int K) {
  __shared__ short As[3][128 * 32];
  __shared__ short Bs[3][BN * 32];
  int bid = blockIdx.y * gridDim.x + blockIdx.x;
  const int nwg = gridDim.x * gridDim.y;
  bid = (bid & 7) * (nwg >> 3) + (bid >> 3);
  const int gn = (bid % gridDim.x) * BN;
  const int gm = (bid / gridDim.x) * 128;

  const int tid = threadIdx.x;
  const int wid = tid >> 6, lane = tid & 63;
  constexpr int MR = (BN == 128) ? 4 : 2;
  const int wm = (BN == 128) ? (wid >> 1) : wid;
  const int wn = (BN == 128) ? (wid & 1) : 0;
  const int fr = lane & 15, kg = lane >> 4;

  const int ldr = lane >> 2;
  const int ldk = (lane & 3) * 8;
  const unsigned short* ap =
      (const unsigned short*)A + (size_t)(gm + wid * 32 + ldr) * K + ldk;
  const unsigned short* bp =
      (const unsigned short*)Bt +
      (size_t)(gn + ((BN == 128) ? wid * 32 : wid * 16) + ldr) * K + ldk;

  const int nkt = K >> 5;

#define STAGE_T(t, buf)                                                    \
  {                                                                        \
    const unsigned short* a_ = ap + (size_t)(t) * 32;                      \
    g2l16((char*)As[buf] + (wid * 2) * 1024, a_);                          \
    g2l16((char*)As[buf] + (wid * 2 + 1) * 1024, a_ + (size_t)16 * K);     \
    const unsigned short* b_ = bp + (size_t)(t) * 32;                      \
    if (BN == 128) {                                                       \
      g2l16((char*)Bs[buf] + (wid * 2) * 1024, b_);                        \
      g2l16((char*)Bs[buf] + (wid * 2 + 1) * 1024, b_ + (size_t)16 * K);   \
    } else {                                                               \
      g2l16((char*)Bs[buf] + wid * 1024, b_);                              \
    }                                                                      \
  }

  // prologue: tiles 0 and 1 in flight
  STAGE_T(0, 0);
  STAGE_T(1, 1);

  f32x4 acc[MR][4] = {};
  for (int t = 0; t < nkt; ++t) {
    const int buf = t % 3;
    if (t + 2 < nkt) STAGE_T(t + 2, (t + 2) % 3);
    // counted wait: only tile t's loads (the oldest LPT) must have landed.
    const int rem = nkt - 1 - t;
    if (rem >= 2) {
      if (BN == 128) asm volatile("s_waitcnt vmcnt(8)" ::: "memory");
      else           asm volatile("s_waitcnt vmcnt(6)" ::: "memory");
    } else if (rem == 1) {
      if (BN == 128) asm volatile("s_waitcnt vmcnt(4)" ::: "memory");
      else           asm volatile("s_waitcnt vmcnt(3)" ::: "memory");
    } else {
      asm volatile("s_waitcnt vmcnt(0)" ::: "memory");
    }
    __builtin_amdgcn_s_barrier();          // all waves' tile-t loads landed
    __builtin_amdgcn_sched_barrier(0);     // keep ds_reads after the barrier
    s16x8 af[MR], bfr[4];
#pragma unroll
    for (int m = 0; m < MR; ++m)
      af[m] = *reinterpret_cast<const s16x8*>(
          &As[buf][(wm * (16 * MR) + m * 16 + fr) * 32 + kg * 8]);
#pragma unroll
    for (int n = 0; n < 4; ++n)
      bfr[n] = *reinterpret_cast<const s16x8*>(
          &Bs[buf][(wn * 64 + n * 16 + fr) * 32 + kg * 8]);
#pragma unroll
    for (int m = 0; m < MR; ++m)
#pragma unroll
      for (int n = 0; n < 4; ++n)
        acc[m][n] = __builtin_amdgcn_mfma_f32_16x16x32_bf16(af[m], bfr[n], acc[m][n], 0, 0, 0);
    __builtin_amdgcn_sched_barrier(0);     // reads of buf done before barrier
    __builtin_amdgcn_s_barrier();          // buf may be overwritten next iter
  }
#undef STAGE_T

  const int r0 = gm + wm * (16 * MR);
  const int c0 = gn + wn * 64;
  float bb[4];
#pragma unroll
  for (int n = 0; n < 4; ++n)
    bb[n] = bias ? bias[c0 + n * 16 + fr] : 0.0f;
#pragma unroll
  for (int m = 0; m < MR; ++m) {
#pragma unroll
    for (int j = 0; j < 4; ++j) {
      const int row = r0 + m * 16 + kg * 4 + j;
#pragma unroll
      for (int n = 0; n < 4; ++n) {
        float val = acc[m][n][j] + bb[n];
        const size_t idx = (size_t)row * N + c0 + n * 16 + fr;
        if (MODE == 0) {
          ((unsigned short*)Cout)[idx] = f2b(val);
        } else if (MODE == 1) {
          float* cp = (float*)Cout + idx;
          *cp = *cp + val;
        } else {
          ((unsigned short*)Cout)[idx] = f2b(gelu_f(val));
        }
      }
    }
  }
}

// ---------------- MFMA flash attention v3: QBLK=128 (unchanged, R6-proven) ----------------
__global__ __launch_bounds__(256) void attn_mfma(
    const __hip_bfloat16* __restrict__ qkv, __hip_bfloat16* __restrict__ yg) {
  const int qb = 7 - blockIdx.x;  // heavy first
  const int hh = blockIdx.y;
  const int bb = blockIdx.z;
  __shared__ short Qs[128 * 64];  // Q staging, then P
  __shared__ short Ks[64 * 64];
  __shared__ short Vt[64 * 64];   // V transposed: row=d, col=k (swizzled)
  const int tid = threadIdx.x;
  const int wid = tid >> 6, lane = tid & 63;
  const int fr = lane & 15, kg = lane >> 4;
  const size_t qb_base = (size_t)bb * T_ * QSTR_ + (size_t)hh * DH_;
  const unsigned short* qgp = (const unsigned short*)qkv + qb_base;
  const unsigned short* kgp = qgp + 1024;
  const unsigned short* vgp = qgp + 2048;
  const float C = 0.125f * 1.4426950408889634f;  // scale * log2(e)

  {
    const int r8 = lane >> 3, cp = lane & 7;
#pragma unroll
    for (int u = 0; u < 4; ++u) {
      const int row = wid * 32 + u * 8 + r8;
      const int c16 = cp ^ (row & 7);
      g2l16((char*)Qs + (wid * 32 + u * 8) * 128,
            qgp + (size_t)(qb * 128 + row) * QSTR_ + c16 * 8);
    }
  }
  asm volatile("s_waitcnt vmcnt(0)" ::: "memory");
  __syncthreads();
  s16x8 qf[2][2];
#pragma unroll
  for (int rg = 0; rg < 2; ++rg) {
    const int row = wid * 32 + rg * 16 + fr;
    const char* rp = (const char*)Qs + row * 128;
    qf[rg][0] = *reinterpret_cast<const s16x8*>(rp + (((0 + kg) ^ (row & 7)) << 4));
    qf[rg][1] = *reinterpret_cast<const s16x8*>(rp + (((4 + kg) ^ (row & 7)) << 4));
  }

  f32x4 acco[2][4] = {};
  float m_run[2][4], l_run[2][4];
#pragma unroll
  for (int rg = 0; rg < 2; ++rg)
#pragma unroll
    for (int j = 0; j < 4; ++j) { m_run[rg][j] = -INFINITY; l_run[rg][j] = 0.f; }

  const int q16hi = qb * 8 + wid * 2 + 1;
  const int ntile = 2 * qb + 2;
  for (int kt = 0; kt < ntile; ++kt) {
    __syncthreads();
    {
      const int r8 = lane >> 3, cp = lane & 7;
#pragma unroll
      for (int u = 0; u < 2; ++u) {
        const int row = wid * 16 + u * 8 + r8;
        const int c16 = cp ^ (row & 7);
        g2l16((char*)Ks + (wid * 16 + u * 8) * 128,
              kgp + (size_t)(kt * 64 + row) * QSTR_ + c16 * 8);
      }
    }
    {
      const int kv0 = tid >> 3;
      const int d0 = (tid & 7) * 8;
      const int rot = tid & 7;
#pragma unroll
      for (int u = 0; u < 2; ++u) {
        const int kv = u * 32 + kv0;
        s16x8 sv = *reinterpret_cast<const s16x8*>(
            vgp + (size_t)(kt * 64 + kv) * QSTR_ + d0);
#pragma unroll
        for (int j = 0; j < 8; ++j) {
          const int jj = (j + rot) & 7;
          const int d = d0 + jj;
          *(short*)((char*)Vt + d * 128 + ((((kv >> 3) ^ jj) & 7) << 4) + (kv & 7) * 2) = sv[jj];
        }
      }
    }
    asm volatile("s_waitcnt vmcnt(0)" ::: "memory");
    __syncthreads();

    if (kt * 4 <= q16hi) {
      f32x4 accs[2][4] = {};
#pragma unroll
      for (int n = 0; n < 4; ++n) {
        const int row = n * 16 + fr;
        const char* rp = (const char*)Ks + row * 128;
        s16x8 kf0 = *reinterpret_cast<const s16x8*>(rp + (((0 + kg) ^ (row & 7)) << 4));
        s16x8 kf1 = *reinterpret_cast<const s16x8*>(rp + (((4 + kg) ^ (row & 7)) << 4));
#pragma unroll
        for (int rg = 0; rg < 2; ++rg) {
          accs[rg][n] = __builtin_amdgcn_mfma_f32_16x16x32_bf16(qf[rg][0], kf0, accs[rg][n], 0, 0, 0);
          accs[rg][n] = __builtin_amdgcn_mfma_f32_16x16x32_bf16(qf[rg][1], kf1, accs[rg][n], 0, 0, 0);
        }
      }
#pragma unroll
      for (int rg = 0; rg < 2; ++rg) {
        const int q16 = qb * 8 + wid * 2 + rg;
        float mloc[4] = {-3.0e38f, -3.0e38f, -3.0e38f, -3.0e38f};
#pragma unroll
        for (int n = 0; n < 4; ++n)
          if (kt * 4 + n <= q16)
#pragma unroll
            for (int j = 0; j < 4; ++j) mloc[j] = fmaxf(mloc[j], accs[rg][n][j]);
#pragma unroll
        for (int off = 1; off < 16; off <<= 1)
#pragma unroll
          for (int j = 0; j < 4; ++j) mloc[j] = fmaxf(mloc[j], __shfl_xor(mloc[j], off));
        float a_[4];
#pragma unroll
        for (int j = 0; j < 4; ++j) {
          const float mn = fmaxf(m_run[rg][j], mloc[j]);
          a_[j] = EXP2F((m_run[rg][j] - mn) * C);
          m_run[rg][j] = mn;
        }
        float psum[4] = {};
#pragma unroll
        for (int n = 0; n < 4; ++n) {
          const bool dead = (kt * 4 + n > q16);
          const int c16b = n * 2 + (fr >> 3);
#pragma unroll
          for (int j = 0; j < 4; ++j) {
            float p = dead ? 0.0f : EXP2F((accs[rg][n][j] - m_run[rg][j]) * C);
            psum[j] += p;
            const int row = wid * 32 + rg * 16 + kg * 4 + j;
            *(short*)((char*)Qs + row * 128 + (((c16b ^ (row & 7)) & 7) << 4) + (fr & 7) * 2) =
                (short)f2b(p);
          }
        }
#pragma unroll
        for (int j = 0; j < 4; ++j) l_run[rg][j] = l_run[rg][j] * a_[j] + psum[j];
#pragma unroll
        for (int dt = 0; dt < 4; ++dt)
#pragma unroll
          for (int j = 0; j < 4; ++j) acco[rg][dt][j] *= a_[j];
      }
#pragma unroll
      for (int rg = 0; rg < 2; ++rg) {
        const int prow = wid * 32 + rg * 16 + fr;
        const char* pp = (const char*)Qs + prow * 128;
#pragma unroll
        for (int kk = 0; kk < 2; ++kk) {
          const s16x8 pf = *reinterpret_cast<const s16x8*>(
              pp + ((((kk * 4 + kg) ^ (prow & 7)) & 7) << 4));
#pragma unroll
          for (int dt = 0; dt < 4; ++dt) {
            const int vrow = dt * 16 + fr;
            const s16x8 vf = *reinterpret_cast<const s16x8*>(
                (const char*)Vt + vrow * 128 + ((((kk * 4 + kg) ^ (vrow & 7)) & 7) << 4));
            acco[rg][dt] = __builtin_amdgcn_mfma_f32_16x16x32_bf16(pf, vf, acco[rg][dt], 0, 0, 0);
          }
        }
      }
    }
  }

#pragma unroll
  for (int off = 1; off < 16; off <<= 1)
#pragma unroll
    for (int rg = 0; rg < 2; ++rg)
#pragma unroll
      for (int j = 0; j < 4; ++j) l_run[rg][j] += __shfl_xor(l_run[rg][j], off);
  unsigned short* yp = (unsigned short*)yg + (size_t)bb * T_ * D_ + (size_t)hh * DH_;
#pragma unroll
  for (int rg = 0; rg < 2; ++rg) {
    float inv[4];
#pragma unroll
    for (int j = 0; j < 4; ++j) inv[j] = 1.0f / l_run[rg][j];
#pragma unroll
    for (int dt = 0; dt < 4; ++dt)
#pragma unroll
      for (int j = 0; j < 4; ++j) {
        const int row = qb * 128 + wid * 32 + rg * 16 + kg * 4 + j;
        yp[(size_t)row * D_ + dt * 16 + fr] = f2b(acco[rg][dt][j] * inv[j]);
      }
  }
}

extern "C" void kernel_launch(void* const* d_in, const int* in_sizes, int n_in,
                              void* d_out, int out_size, void* d_ws, size_t ws_size,
                              hipStream_t stream) {
  (void)in_sizes; (void)n_in; (void)out_size; (void)ws_size;
  const float* seq  = (const float*)d_in[0];
  const float* Wq   = (const float*)d_in[1];
  const float* bq   = (const float*)d_in[2];
  const float* Wk   = (const float*)d_in[3];
  const float* bk   = (const float*)d_in[4];
  const float* Wv   = (const float*)d_in[5];
  const float* bv   = (const float*)d_in[6];
  const float* Wp   = (const float*)d_in[7];
  const float* bp   = (const float*)d_in[8];
  const float* ln1g = (const float*)d_in[9];
  const float* ln1b = (const float*)d_in[10];
  const float* ln2g = (const float*)d_in[11];
  const float* ln2b = (const float*)d_in[12];
  const float* W1   = (const float*)d_in[13];
  const float* b1   = (const float*)d_in[14];
  const float* W2   = (const float*)d_in[15];
  const float* b2   = (const float*)d_in[16];
  const float* lnfg = (const float*)d_in[17];
  const float* lnfb = (const float*)d_in[18];

  float* x = (float*)d_out;
  char* ws = (char*)d_ws;
  const size_t MB = 1024ull * 1024ull;
  typedef __hip_bfloat16 bf16;
  bf16*  wtqkv = (bf16*)(ws + 0 * MB);    // [3072][1024]
  bf16*  wtp   = (bf16*)(ws + 6 * MB);    // [1024][1024]
  bf16*  wtF1  = (bf16*)(ws + 8 * MB);    // [4096][1024]
  bf16*  wtF2  = (bf16*)(ws + 16 * MB);   // [1024][4096]
  bf16*  hb    = (bf16*)(ws + 24 * MB);   // [4096][1024]
  bf16*  qkv   = (bf16*)(ws + 32 * MB);   // [4096][3072]
  bf16*  mid   = (bf16*)(ws + 56 * MB);   // [4096][4096]
  float* bqkv  = (float*)(ws + 88 * MB);  // [8][3072]

  hipMemcpyAsync(x, seq, (size_t)M_ * D_ * sizeof(float), hipMemcpyDeviceToDevice, stream);

  const dim3 blk(256);
  concat_bias<<<96, blk, 0, stream>>>(bq, bk, bv, bqkv);

  for (int i = 0; i < 8; ++i) {
    const size_t wo  = (size_t)i * D_ * D_;
    const size_t vo  = (size_t)i * D_;
    const size_t w1o = (size_t)i * D_ * 4 * D_;

    ln_kernel<true><<<M_, blk, 0, stream>>>(x, hb, ln1g + vo, ln1b + vo);
    TrAll ta;
    ta.wq = Wq + wo; ta.wk = Wk + wo; ta.wv = Wv + wo; ta.wp = Wp + wo;
    ta.w1 = W1 + w1o; ta.w2 = W2 + w1o;
    ta.dqkv = wtqkv; ta.dp = wtp; ta.d1 = wtF1; ta.d2 = wtF2;
    transpose_all<<<12288, blk, 0, stream>>>(ta);
    gemm_mfma<0, 128><<<dim3(24, 32), blk, 0, stream>>>(
        hb, wtqkv, bqkv + (size_t)i * QSTR_, qkv, QSTR_, 1024);
    attn_mfma<<<dim3(8, 16, 4), blk, 0, stream>>>(qkv, hb);
    gemm_mfma<1, 64><<<dim3(16, 32), blk, 0, stream>>>(hb, wtp, bp + vo, x, 1024, 1024);
    ln_kernel<true><<<M_, blk, 0, stream>>>(x, hb, ln2g + vo, ln2b + vo);
    gemm_mfma<2, 128><<<dim3(32, 32), blk, 0, stream>>>(
        hb, wtF1, b1 + (size_t)i * 4096, mid, 4096, 1024);
    gemm_mfma<1, 64><<<dim3(16, 32), blk, 0, stream>>>(
        mid, wtF2, b2 + vo, x, 1024, 4096);
  }
  ln_kernel<false><<<M_, blk, 0, stream>>>(x, x, lnfg, lnfb);
}

// Round 8
// 2292.008 us; speedup vs baseline: 1.0140x; 1.0140x over previous
//
#include <hip/hip_runtime.h>
#include <hip/hip_bf16.h>
#include <math.h>

#define B_ 4
#define T_ 1024
#define D_ 1024
#define H_ 16
#define DH_ 64
#define M_ 4096
#define QSTR_ 3072   // fused qkv row stride
#define EPS_ 1e-5f

typedef __attribute__((ext_vector_type(4))) float f32x4;
typedef __attribute__((ext_vector_type(8))) short s16x8;

#if __has_builtin(__builtin_amdgcn_exp2f)
#define EXP2F __builtin_amdgcn_exp2f
#else
#define EXP2F exp2f
#endif

__device__ __forceinline__ float gelu_f(float x) {
  return 0.5f * x * (1.0f + erff(x * 0.70710678118654752f));
}
__device__ __forceinline__ float b2f(unsigned short u) {
  union { unsigned int i; float f; } c; c.i = ((unsigned int)u) << 16; return c.f;
}
__device__ __forceinline__ unsigned short f2b(float f) {
  __hip_bfloat16 h = __float2bfloat16(f);
  return *reinterpret_cast<unsigned short*>(&h);
}
__device__ __forceinline__ void g2l16(void* l, const void* g) {
  __builtin_amdgcn_global_load_lds(
      (const __attribute__((address_space(1))) void*)g,
      (__attribute__((address_space(3))) void*)l, 16, 0, 0);
}

// ---------------- LayerNorm ----------------
template<bool BF16OUT>
__global__ __launch_bounds__(256) void ln_kernel(
    const float* __restrict__ in, void* __restrict__ out,
    const float* __restrict__ g, const float* __restrict__ b) {
  const int row = blockIdx.x;
  const int tid = threadIdx.x;
  const float* rp = in + (size_t)row * D_;
  float4 v = *reinterpret_cast<const float4*>(rp + tid * 4);
  float s = v.x + v.y + v.z + v.w;
  float s2 = v.x * v.x + v.y * v.y + v.z * v.z + v.w * v.w;
#pragma unroll
  for (int off = 1; off < 64; off <<= 1) {
    s += __shfl_xor(s, off);
    s2 += __shfl_xor(s2, off);
  }
  __shared__ float red[2][4];
  const int wid = tid >> 6;
  if ((tid & 63) == 0) { red[0][wid] = s; red[1][wid] = s2; }
  __syncthreads();
  s = red[0][0] + red[0][1] + red[0][2] + red[0][3];
  s2 = red[1][0] + red[1][1] + red[1][2] + red[1][3];
  const float mu = s * (1.0f / D_);
  const float var = s2 * (1.0f / D_) - mu * mu;
  const float rs = rsqrtf(var + EPS_);
  float4 gv = *reinterpret_cast<const float4*>(g + tid * 4);
  float4 bv = *reinterpret_cast<const float4*>(b + tid * 4);
  float o0 = (v.x - mu) * rs * gv.x + bv.x;
  float o1 = (v.y - mu) * rs * gv.y + bv.y;
  float o2 = (v.z - mu) * rs * gv.z + bv.z;
  float o3 = (v.w - mu) * rs * gv.w + bv.w;
  if (BF16OUT) {
    ushort4 pk;
    pk.x = f2b(o0); pk.y = f2b(o1); pk.z = f2b(o2); pk.w = f2b(o3);
    *reinterpret_cast<ushort4*>((unsigned short*)out + (size_t)row * D_ + tid * 4) = pk;
  } else {
    *reinterpret_cast<float4*>((float*)out + (size_t)row * D_ + tid * 4) =
        make_float4(o0, o1, o2, o3);
  }
}

// ---------------- bias concat: [L][3072] <- bq|bk|bv ----------------
__global__ __launch_bounds__(256) void concat_bias(
    const float* __restrict__ bq, const float* __restrict__ bk,
    const float* __restrict__ bv, float* __restrict__ out) {
  const int i = blockIdx.x * 256 + threadIdx.x;
  const int l = i / QSTR_, c = i % QSTR_;
  const float* src = (c < 1024) ? bq : ((c < 2048) ? bk : bv);
  out[i] = src[l * 1024 + (c & 1023)];
}

// ---------------- all weight transposes for one layer, single launch ----------------
__device__ __forceinline__ void transpose_tile(
    const float* __restrict__ src, int sld,
    __hip_bfloat16* __restrict__ dst, int dld, int k0, int n0) {
  __shared__ float tile[32][33];
  const int t = threadIdx.x;
  const int r = t >> 3;
  const int cq = (t & 7) * 4;
  float4 vv = *reinterpret_cast<const float4*>(src + (size_t)(k0 + r) * sld + n0 + cq);
  tile[r][cq + 0] = vv.x; tile[r][cq + 1] = vv.y;
  tile[r][cq + 2] = vv.z; tile[r][cq + 3] = vv.w;
  __syncthreads();
  ushort4 o;
  o.x = f2b(tile[cq + 0][r]); o.y = f2b(tile[cq + 1][r]);
  o.z = f2b(tile[cq + 2][r]); o.w = f2b(tile[cq + 3][r]);
  *reinterpret_cast<ushort4*>((unsigned short*)dst + (size_t)(n0 + r) * dld + k0 + cq) = o;
}

struct TrAll {
  const float *wq, *wk, *wv, *wp, *w1, *w2;
  __hip_bfloat16 *dqkv, *dp, *d1, *d2;
};

__global__ __launch_bounds__(256) void transpose_all(TrAll a) {
  const int t = blockIdx.x;
  const float* src;
  __hip_bfloat16* dst;
  int sld, dld, k0, n0;
  if (t < 4096) {
    const int m = t >> 10, tile = t & 1023;
    k0 = (tile >> 5) * 32; n0 = (tile & 31) * 32;
    src = (m == 0) ? a.wq : (m == 1) ? a.wk : (m == 2) ? a.wv : a.wp;
    sld = 1024; dld = 1024;
    dst = (m < 3) ? (a.dqkv + (size_t)m * 1024 * 1024) : a.dp;
  } else if (t < 8192) {
    const int tile = t - 4096;
    k0 = (tile & 31) * 32; n0 = (tile >> 5) * 32;
    src = a.w1; sld = 4096; dst = a.d1; dld = 1024;
  } else {
    const int tile = t - 8192;
    k0 = (tile >> 5) * 32; n0 = (tile & 31) * 32;
    src = a.w2; sld = 1024; dst = a.d2; dld = 4096;
  }
  transpose_tile(src, sld, dst, dld, k0, n0);
}

// ---------------- bf16 MFMA GEMM: 3-deep pipeline + T2 chunk-XOR swizzle ----------
// LDS tile rows are 64B (32 bf16). 16B-chunk c of row r stored at c ^ ((r>>1)&3):
//   write side = pre-swizzled GLOBAL k-offset (dest stays linear for global_load_lds),
//   read side  = fragment chunk kg ^ ((fr>>1)&3).  -> 2 lanes/bank (conflict-free).
// MODE 0: store bf16; MODE 1: fp32 C += result; MODE 2: store bf16 gelu(result)
template<int MODE, int BN>
__global__ __launch_bounds__(256) void gemm_mfma(
    const __hip_bfloat16* __restrict__ A,
    const __hip_bfloat16* __restrict__ Bt,
    const float* __restrict__ bias,
    void* __restrict__ Cout, int N, int K) {
  __shared__ short As[3][128 * 32];
  __shared__ short Bs[3][BN * 32];
  int bid = blockIdx.y * gridDim.x + blockIdx.x;
  const int nwg = gridDim.x * gridDim.y;
  bid = (bid & 7) * (nwg >> 3) + (bid >> 3);
  const int gn = (bid % gridDim.x) * BN;
  const int gm = (bid / gridDim.x) * 128;

  const int tid = threadIdx.x;
  const int wid = tid >> 6, lane = tid & 63;
  constexpr int MR = (BN == 128) ? 4 : 2;
  const int wm = (BN == 128) ? (wid >> 1) : wid;
  const int wn = (BN == 128) ? (wid & 1) : 0;
  const int fr = lane & 15, kg = lane >> 4;

  const int ldr = lane >> 2;                               // row within 16-row group
  const int ldk = (((lane & 3) ^ ((lane >> 3) & 3)) * 8);  // pre-swizzled source chunk
  const unsigned short* ap =
      (const unsigned short*)A + (size_t)(gm + wid * 32 + ldr) * K + ldk;
  const unsigned short* bp =
      (const unsigned short*)Bt +
      (size_t)(gn + ((BN == 128) ? wid * 32 : wid * 16) + ldr) * K + ldk;

  const int nkt = K >> 5;

#define STAGE_T(t, buf)                                                    \
  {                                                                        \
    const unsigned short* a_ = ap + (size_t)(t) * 32;                      \
    g2l16((char*)As[buf] + (wid * 2) * 1024, a_);                          \
    g2l16((char*)As[buf] + (wid * 2 + 1) * 1024, a_ + (size_t)16 * K);     \
    const unsigned short* b_ = bp + (size_t)(t) * 32;                      \
    if (BN == 128) {                                                       \
      g2l16((char*)Bs[buf] + (wid * 2) * 1024, b_);                        \
      g2l16((char*)Bs[buf] + (wid * 2 + 1) * 1024, b_ + (size_t)16 * K);   \
    } else {                                                               \
      g2l16((char*)Bs[buf] + wid * 1024, b_);                              \
    }                                                                      \
  }

  // prologue: tiles 0 and 1 in flight
  STAGE_T(0, 0);
  STAGE_T(1, 1);

  const int cxa = (kg ^ ((fr >> 1) & 3)) * 8;  // swizzled read chunk (shorts)
  f32x4 acc[MR][4] = {};
  for (int t = 0; t < nkt; ++t) {
    const int buf = t % 3;
    if (t + 2 < nkt) STAGE_T(t + 2, (t + 2) % 3);
    // counted wait: only tile t's loads (the oldest in queue) must have landed.
    const int rem = nkt - 1 - t;
    if (rem >= 2) {
      if (BN == 128) asm volatile("s_waitcnt vmcnt(8)" ::: "memory");
      else           asm volatile("s_waitcnt vmcnt(6)" ::: "memory");
    } else if (rem == 1) {
      if (BN == 128) asm volatile("s_waitcnt vmcnt(4)" ::: "memory");
      else           asm volatile("s_waitcnt vmcnt(3)" ::: "memory");
    } else {
      asm volatile("s_waitcnt vmcnt(0)" ::: "memory");
    }
    __builtin_amdgcn_s_barrier();          // all waves' tile-t loads landed
    __builtin_amdgcn_sched_barrier(0);     // keep ds_reads after the barrier
    s16x8 af[MR], bfr[4];
#pragma unroll
    for (int m = 0; m < MR; ++m)
      af[m] = *reinterpret_cast<const s16x8*>(
          &As[buf][(wm * (16 * MR) + m * 16 + fr) * 32 + cxa]);
#pragma unroll
    for (int n = 0; n < 4; ++n)
      bfr[n] = *reinterpret_cast<const s16x8*>(
          &Bs[buf][(wn * 64 + n * 16 + fr) * 32 + cxa]);
#pragma unroll
    for (int m = 0; m < MR; ++m)
#pragma unroll
      for (int n = 0; n < 4; ++n)
        acc[m][n] = __builtin_amdgcn_mfma_f32_16x16x32_bf16(af[m], bfr[n], acc[m][n], 0, 0, 0);
    __builtin_amdgcn_sched_barrier(0);     // reads of buf done before barrier
    __builtin_amdgcn_s_barrier();          // buf may be overwritten next iter
  }
#undef STAGE_T

  const int r0 = gm + wm * (16 * MR);
  const int c0 = gn + wn * 64;
  float bb[4];
#pragma unroll
  for (int n = 0; n < 4; ++n)
    bb[n] = bias ? bias[c0 + n * 16 + fr] : 0.0f;
#pragma unroll
  for (int m = 0; m < MR; ++m) {
#pragma unroll
    for (int j = 0; j < 4; ++j) {
      const int row = r0 + m * 16 + kg * 4 + j;
#pragma unroll
      for (int n = 0; n < 4; ++n) {
        float val = acc[m][n][j] + bb[n];
        const size_t idx = (size_t)row * N + c0 + n * 16 + fr;
        if (MODE == 0) {
          ((unsigned short*)Cout)[idx] = f2b(val);
        } else if (MODE == 1) {
          float* cp = (float*)Cout + idx;
          *cp = *cp + val;
        } else {
          ((unsigned short*)Cout)[idx] = f2b(gelu_f(val));
        }
      }
    }
  }
}

// ---------------- MFMA flash attention v3: QBLK=128 (unchanged, R6-proven) ----------------
__global__ __launch_bounds__(256) void attn_mfma(
    const __hip_bfloat16* __restrict__ qkv, __hip_bfloat16* __restrict__ yg) {
  const int qb = 7 - blockIdx.x;  // heavy first
  const int hh = blockIdx.y;
  const int bb = blockIdx.z;
  __shared__ short Qs[128 * 64];  // Q staging, then P
  __shared__ short Ks[64 * 64];
  __shared__ short Vt[64 * 64];   // V transposed: row=d, col=k (swizzled)
  const int tid = threadIdx.x;
  const int wid = tid >> 6, lane = tid & 63;
  const int fr = lane & 15, kg = lane >> 4;
  const size_t qb_base = (size_t)bb * T_ * QSTR_ + (size_t)hh * DH_;
  const unsigned short* qgp = (const unsigned short*)qkv + qb_base;
  const unsigned short* kgp = qgp + 1024;
  const unsigned short* vgp = qgp + 2048;
  const float C = 0.125f * 1.4426950408889634f;  // scale * log2(e)

  {
    const int r8 = lane >> 3, cp = lane & 7;
#pragma unroll
    for (int u = 0; u < 4; ++u) {
      const int row = wid * 32 + u * 8 + r8;
      const int c16 = cp ^ (row & 7);
      g2l16((char*)Qs + (wid * 32 + u * 8) * 128,
            qgp + (size_t)(qb * 128 + row) * QSTR_ + c16 * 8);
    }
  }
  asm volatile("s_waitcnt vmcnt(0)" ::: "memory");
  __syncthreads();
  s16x8 qf[2][2];
#pragma unroll
  for (int rg = 0; rg < 2; ++rg) {
    const int row = wid * 32 + rg * 16 + fr;
    const char* rp = (const char*)Qs + row * 128;
    qf[rg][0] = *reinterpret_cast<const s16x8*>(rp + (((0 + kg) ^ (row & 7)) << 4));
    qf[rg][1] = *reinterpret_cast<const s16x8*>(rp + (((4 + kg) ^ (row & 7)) << 4));
  }

  f32x4 acco[2][4] = {};
  float m_run[2][4], l_run[2][4];
#pragma unroll
  for (int rg = 0; rg < 2; ++rg)
#pragma unroll
    for (int j = 0; j < 4; ++j) { m_run[rg][j] = -INFINITY; l_run[rg][j] = 0.f; }

  const int q16hi = qb * 8 + wid * 2 + 1;
  const int ntile = 2 * qb + 2;
  for (int kt = 0; kt < ntile; ++kt) {
    __syncthreads();
    {
      const int r8 = lane >> 3, cp = lane & 7;
#pragma unroll
      for (int u = 0; u < 2; ++u) {
        const int row = wid * 16 + u * 8 + r8;
        const int c16 = cp ^ (row & 7);
        g2l16((char*)Ks + (wid * 16 + u * 8) * 128,
              kgp + (size_t)(kt * 64 + row) * QSTR_ + c16 * 8);
      }
    }
    {
      const int kv0 = tid >> 3;
      const int d0 = (tid & 7) * 8;
      const int rot = tid & 7;
#pragma unroll
      for (int u = 0; u < 2; ++u) {
        const int kv = u * 32 + kv0;
        s16x8 sv = *reinterpret_cast<const s16x8*>(
            vgp + (size_t)(kt * 64 + kv) * QSTR_ + d0);
#pragma unroll
        for (int j = 0; j < 8; ++j) {
          const int jj = (j + rot) & 7;
          const int d = d0 + jj;
          *(short*)((char*)Vt + d * 128 + ((((kv >> 3) ^ jj) & 7) << 4) + (kv & 7) * 2) = sv[jj];
        }
      }
    }
    asm volatile("s_waitcnt vmcnt(0)" ::: "memory");
    __syncthreads();

    if (kt * 4 <= q16hi) {
      f32x4 accs[2][4] = {};
#pragma unroll
      for (int n = 0; n < 4; ++n) {
        const int row = n * 16 + fr;
        const char* rp = (const char*)Ks + row * 128;
        s16x8 kf0 = *reinterpret_cast<const s16x8*>(rp + (((0 + kg) ^ (row & 7)) << 4));
        s16x8 kf1 = *reinterpret_cast<const s16x8*>(rp + (((4 + kg) ^ (row & 7)) << 4));
#pragma unroll
        for (int rg = 0; rg < 2; ++rg) {
          accs[rg][n] = __builtin_amdgcn_mfma_f32_16x16x32_bf16(qf[rg][0], kf0, accs[rg][n], 0, 0, 0);
          accs[rg][n] = __builtin_amdgcn_mfma_f32_16x16x32_bf16(qf[rg][1], kf1, accs[rg][n], 0, 0, 0);
        }
      }
#pragma unroll
      for (int rg = 0; rg < 2; ++rg) {
        const int q16 = qb * 8 + wid * 2 + rg;
        float mloc[4] = {-3.0e38f, -3.0e38f, -3.0e38f, -3.0e38f};
#pragma unroll
        for (int n = 0; n < 4; ++n)
          if (kt * 4 + n <= q16)
#pragma unroll
            for (int j = 0; j < 4; ++j) mloc[j] = fmaxf(mloc[j], accs[rg][n][j]);
#pragma unroll
        for (int off = 1; off < 16; off <<= 1)
#pragma unroll
          for (int j = 0; j < 4; ++j) mloc[j] = fmaxf(mloc[j], __shfl_xor(mloc[j], off));
        float a_[4];
#pragma unroll
        for (int j = 0; j < 4; ++j) {
          const float mn = fmaxf(m_run[rg][j], mloc[j]);
          a_[j] = EXP2F((m_run[rg][j] - mn) * C);
          m_run[rg][j] = mn;
        }
        float psum[4] = {};
#pragma unroll
        for (int n = 0; n < 4; ++n) {
          const bool dead = (kt * 4 + n > q16);
          const int c16b = n * 2 + (fr >> 3);
#pragma unroll
          for (int j = 0; j < 4; ++j) {
            float p = dead ? 0.0f : EXP2F((accs[rg][n][j] - m_run[rg][j]) * C);
            psum[j] += p;
            const int row = wid * 32 + rg * 16 + kg * 4 + j;
            *(short*)((char*)Qs + row * 128 + (((c16b ^ (row & 7)) & 7) << 4) + (fr & 7) * 2) =
                (short)f2b(p);
          }
        }
#pragma unroll
        for (int j = 0; j < 4; ++j) l_run[rg][j] = l_run[rg][j] * a_[j] + psum[j];
#pragma unroll
        for (int dt = 0; dt < 4; ++dt)
#pragma unroll
          for (int j = 0; j < 4; ++j) acco[rg][dt][j] *= a_[j];
      }
#pragma unroll
      for (int rg = 0; rg < 2; ++rg) {
        const int prow = wid * 32 + rg * 16 + fr;
        const char* pp = (const char*)Qs + prow * 128;
#pragma unroll
        for (int kk = 0; kk < 2; ++kk) {
          const s16x8 pf = *reinterpret_cast<const s16x8*>(
              pp + ((((kk * 4 + kg) ^ (prow & 7)) & 7) << 4));
#pragma unroll
          for (int dt = 0; dt < 4; ++dt) {
            const int vrow = dt * 16 + fr;
            const s16x8 vf = *reinterpret_cast<const s16x8*>(
                (const char*)Vt + vrow * 128 + ((((kk * 4 + kg) ^ (vrow & 7)) & 7) << 4));
            acco[rg][dt] = __builtin_amdgcn_mfma_f32_16x16x32_bf16(pf, vf, acco[rg][dt], 0, 0, 0);
          }
        }
      }
    }
  }

#pragma unroll
  for (int off = 1; off < 16; off <<= 1)
#pragma unroll
    for (int rg = 0; rg < 2; ++rg)
#pragma unroll
      for (int j = 0; j < 4; ++j) l_run[rg][j] += __shfl_xor(l_run[rg][j], off);
  unsigned short* yp = (unsigned short*)yg + (size_t)bb * T_ * D_ + (size_t)hh * DH_;
#pragma unroll
  for (int rg = 0; rg < 2; ++rg) {
    float inv[4];
#pragma unroll
    for (int j = 0; j < 4; ++j) inv[j] = 1.0f / l_run[rg][j];
#pragma unroll
    for (int dt = 0; dt < 4; ++dt)
#pragma unroll
      for (int j = 0; j < 4; ++j) {
        const int row = qb * 128 + wid * 32 + rg * 16 + kg * 4 + j;
        yp[(size_t)row * D_ + dt * 16 + fr] = f2b(acco[rg][dt][j] * inv[j]);
      }
  }
}

extern "C" void kernel_launch(void* const* d_in, const int* in_sizes, int n_in,
                              void* d_out, int out_size, void* d_ws, size_t ws_size,
                              hipStream_t stream) {
  (void)in_sizes; (void)n_in; (void)out_size; (void)ws_size;
  const float* seq  = (const float*)d_in[0];
  const float* Wq   = (const float*)d_in[1];
  const float* bq   = (const float*)d_in[2];
  const float* Wk   = (const float*)d_in[3];
  const float* bk   = (const float*)d_in[4];
  const float* Wv   = (const float*)d_in[5];
  const float* bv   = (const float*)d_in[6];
  const float* Wp   = (const float*)d_in[7];
  const float* bp   = (const float*)d_in[8];
  const float* ln1g = (const float*)d_in[9];
  const float* ln1b = (const float*)d_in[10];
  const float* ln2g = (const float*)d_in[11];
  const float* ln2b = (const float*)d_in[12];
  const float* W1   = (const float*)d_in[13];
  const float* b1   = (const float*)d_in[14];
  const float* W2   = (const float*)d_in[15];
  const float* b2   = (const float*)d_in[16];
  const float* lnfg = (const float*)d_in[17];
  const float* lnfb = (const float*)d_in[18];

  float* x = (float*)d_out;
  char* ws = (char*)d_ws;
  const size_t MB = 1024ull * 1024ull;
  typedef __hip_bfloat16 bf16;
  bf16*  wtqkv = (bf16*)(ws + 0 * MB);    // [3072][1024]
  bf16*  wtp   = (bf16*)(ws + 6 * MB);    // [1024][1024]
  bf16*  wtF1  = (bf16*)(ws + 8 * MB);    // [4096][1024]
  bf16*  wtF2  = (bf16*)(ws + 16 * MB);   // [1024][4096]
  bf16*  hb    = (bf16*)(ws + 24 * MB);   // [4096][1024]
  bf16*  qkv   = (bf16*)(ws + 32 * MB);   // [4096][3072]
  bf16*  mid   = (bf16*)(ws + 56 * MB);   // [4096][4096]
  float* bqkv  = (float*)(ws + 88 * MB);  // [8][3072]

  hipMemcpyAsync(x, seq, (size_t)M_ * D_ * sizeof(float), hipMemcpyDeviceToDevice, stream);

  const dim3 blk(256);
  concat_bias<<<96, blk, 0, stream>>>(bq, bk, bv, bqkv);

  for (int i = 0; i < 8; ++i) {
    const size_t wo  = (size_t)i * D_ * D_;
    const size_t vo  = (size_t)i * D_;
    const size_t w1o = (size_t)i * D_ * 4 * D_;

    ln_kernel<true><<<M_, blk, 0, stream>>>(x, hb, ln1g + vo, ln1b + vo);
    TrAll ta;
    ta.wq = Wq + wo; ta.wk = Wk + wo; ta.wv = Wv + wo; ta.wp = Wp + wo;
    ta.w1 = W1 + w1o; ta.w2 = W2 + w1o;
    ta.dqkv = wtqkv; ta.dp = wtp; ta.d1 = wtF1; ta.d2 = wtF2;
    transpose_all<<<12288, blk, 0, stream>>>(ta);
    gemm_mfma<0, 128><<<dim3(24, 32), blk, 0, stream>>>(
        hb, wtqkv, bqkv + (size_t)i * QSTR_, qkv, QSTR_, 1024);
    attn_mfma<<<dim3(8, 16, 4), blk, 0, stream>>>(qkv, hb);
    gemm_mfma<1, 64><<<dim3(16, 32), blk, 0, stream>>>(hb, wtp, bp + vo, x, 1024, 1024);
    ln_kernel<true><<<M_, blk, 0, stream>>>(x, hb, ln2g + vo, ln2b + vo);
    gemm_mfma<2, 128><<<dim3(32, 32), blk, 0, stream>>>(
        hb, wtF1, b1 + (size_t)i * 4096, mid, 4096, 1024);
    gemm_mfma<1, 64><<<dim3(16, 32), blk, 0, stream>>>(
        mid, wtF2, b2 + vo, x, 1024, 4096);
  }
  ln_kernel<false><<<M_, blk, 0, stream>>>(x, x, lnfg, lnfb);
}

// Round 9
// 2240.678 us; speedup vs baseline: 1.0372x; 1.0229x over previous
//
#include <hip/hip_runtime.h>
#include <hip/hip_bf16.h>
#include <math.h>

#define B_ 4
#define T_ 1024
#define D_ 1024
#define H_ 16
#define DH_ 64
#define M_ 4096
#define QSTR_ 3072   // fused qkv row stride
#define EPS_ 1e-5f

typedef __attribute__((ext_vector_type(4))) float f32x4;
typedef __attribute__((ext_vector_type(8))) short s16x8;

#if __has_builtin(__builtin_amdgcn_exp2f)
#define EXP2F __builtin_amdgcn_exp2f
#else
#define EXP2F exp2f
#endif

__device__ __forceinline__ float gelu_f(float x) {
  return 0.5f * x * (1.0f + erff(x * 0.70710678118654752f));
}
__device__ __forceinline__ float b2f(unsigned short u) {
  union { unsigned int i; float f; } c; c.i = ((unsigned int)u) << 16; return c.f;
}
__device__ __forceinline__ unsigned short f2b(float f) {
  __hip_bfloat16 h = __float2bfloat16(f);
  return *reinterpret_cast<unsigned short*>(&h);
}
__device__ __forceinline__ void g2l16(void* l, const void* g) {
  __builtin_amdgcn_global_load_lds(
      (const __attribute__((address_space(1))) void*)g,
      (__attribute__((address_space(3))) void*)l, 16, 0, 0);
}

// ---------------- LayerNorm ----------------
template<bool BF16OUT>
__global__ __launch_bounds__(256) void ln_kernel(
    const float* __restrict__ in, void* __restrict__ out,
    const float* __restrict__ g, const float* __restrict__ b) {
  const int row = blockIdx.x;
  const int tid = threadIdx.x;
  const float* rp = in + (size_t)row * D_;
  float4 v = *reinterpret_cast<const float4*>(rp + tid * 4);
  float s = v.x + v.y + v.z + v.w;
  float s2 = v.x * v.x + v.y * v.y + v.z * v.z + v.w * v.w;
#pragma unroll
  for (int off = 1; off < 64; off <<= 1) {
    s += __shfl_xor(s, off);
    s2 += __shfl_xor(s2, off);
  }
  __shared__ float red[2][4];
  const int wid = tid >> 6;
  if ((tid & 63) == 0) { red[0][wid] = s; red[1][wid] = s2; }
  __syncthreads();
  s = red[0][0] + red[0][1] + red[0][2] + red[0][3];
  s2 = red[1][0] + red[1][1] + red[1][2] + red[1][3];
  const float mu = s * (1.0f / D_);
  const float var = s2 * (1.0f / D_) - mu * mu;
  const float rs = rsqrtf(var + EPS_);
  float4 gv = *reinterpret_cast<const float4*>(g + tid * 4);
  float4 bv = *reinterpret_cast<const float4*>(b + tid * 4);
  float o0 = (v.x - mu) * rs * gv.x + bv.x;
  float o1 = (v.y - mu) * rs * gv.y + bv.y;
  float o2 = (v.z - mu) * rs * gv.z + bv.z;
  float o3 = (v.w - mu) * rs * gv.w + bv.w;
  if (BF16OUT) {
    ushort4 pk;
    pk.x = f2b(o0); pk.y = f2b(o1); pk.z = f2b(o2); pk.w = f2b(o3);
    *reinterpret_cast<ushort4*>((unsigned short*)out + (size_t)row * D_ + tid * 4) = pk;
  } else {
    *reinterpret_cast<float4*>((float*)out + (size_t)row * D_ + tid * 4) =
        make_float4(o0, o1, o2, o3);
  }
}

// ---------------- bias concat: [L][3072] <- bq|bk|bv ----------------
__global__ __launch_bounds__(256) void concat_bias(
    const float* __restrict__ bq, const float* __restrict__ bk,
    const float* __restrict__ bv, float* __restrict__ out) {
  const int i = blockIdx.x * 256 + threadIdx.x;
  const int l = i / QSTR_, c = i % QSTR_;
  const float* src = (c < 1024) ? bq : ((c < 2048) ? bk : bv);
  out[i] = src[l * 1024 + (c & 1023)];
}

// ---------------- x += partial (split-K reduction, deterministic) ----------------
__global__ __launch_bounds__(256) void reduce_add(
    float* __restrict__ x, const float* __restrict__ p) {
  const int i = blockIdx.x * 256 + threadIdx.x;
  float4 a = reinterpret_cast<float4*>(x)[i];
  float4 b = reinterpret_cast<const float4*>(p)[i];
  a.x += b.x; a.y += b.y; a.z += b.z; a.w += b.w;
  reinterpret_cast<float4*>(x)[i] = a;
}

// ---------------- all weight transposes for one layer, single launch ----------------
__device__ __forceinline__ void transpose_tile(
    const float* __restrict__ src, int sld,
    __hip_bfloat16* __restrict__ dst, int dld, int k0, int n0) {
  __shared__ float tile[32][33];
  const int t = threadIdx.x;
  const int r = t >> 3;
  const int cq = (t & 7) * 4;
  float4 vv = *reinterpret_cast<const float4*>(src + (size_t)(k0 + r) * sld + n0 + cq);
  tile[r][cq + 0] = vv.x; tile[r][cq + 1] = vv.y;
  tile[r][cq + 2] = vv.z; tile[r][cq + 3] = vv.w;
  __syncthreads();
  ushort4 o;
  o.x = f2b(tile[cq + 0][r]); o.y = f2b(tile[cq + 1][r]);
  o.z = f2b(tile[cq + 2][r]); o.w = f2b(tile[cq + 3][r]);
  *reinterpret_cast<ushort4*>((unsigned short*)dst + (size_t)(n0 + r) * dld + k0 + cq) = o;
}

struct TrAll {
  const float *wq, *wk, *wv, *wp, *w1, *w2;
  __hip_bfloat16 *dqkv, *dp, *d1, *d2;
};

__global__ __launch_bounds__(256) void transpose_all(TrAll a) {
  const int t = blockIdx.x;
  const float* src;
  __hip_bfloat16* dst;
  int sld, dld, k0, n0;
  if (t < 4096) {
    const int m = t >> 10, tile = t & 1023;
    k0 = (tile >> 5) * 32; n0 = (tile & 31) * 32;
    src = (m == 0) ? a.wq : (m == 1) ? a.wk : (m == 2) ? a.wv : a.wp;
    sld = 1024; dld = 1024;
    dst = (m < 3) ? (a.dqkv + (size_t)m * 1024 * 1024) : a.dp;
  } else if (t < 8192) {
    const int tile = t - 4096;
    k0 = (tile & 31) * 32; n0 = (tile >> 5) * 32;
    src = a.w1; sld = 4096; dst = a.d1; dld = 1024;
  } else {
    const int tile = t - 8192;
    k0 = (tile >> 5) * 32; n0 = (tile & 31) * 32;
    src = a.w2; sld = 1024; dst = a.d2; dld = 4096;
  }
  transpose_tile(src, sld, dst, dld, k0, n0);
}

// ---------------- bf16 MFMA GEMM: 3-deep pipeline + chunk-XOR swizzle ----------
// MODE 0: store bf16; MODE 1: fp32 C += result; MODE 2: store bf16 gelu(result)
template<int MODE, int BN>
__global__ __launch_bounds__(256) void gemm_mfma(
    const __hip_bfloat16* __restrict__ A,
    const __hip_bfloat16* __restrict__ Bt,
    const float* __restrict__ bias,
    void* __restrict__ Cout, int N, int K) {
  __shared__ short As[3][128 * 32];
  __shared__ short Bs[3][BN * 32];
  int bid = blockIdx.y * gridDim.x + blockIdx.x;
  const int nwg = gridDim.x * gridDim.y;
  bid = (bid & 7) * (nwg >> 3) + (bid >> 3);
  const int gn = (bid % gridDim.x) * BN;
  const int gm = (bid / gridDim.x) * 128;

  const int tid = threadIdx.x;
  const int wid = tid >> 6, lane = tid & 63;
  constexpr int MR = (BN == 128) ? 4 : 2;
  const int wm = (BN == 128) ? (wid >> 1) : wid;
  const int wn = (BN == 128) ? (wid & 1) : 0;
  const int fr = lane & 15, kg = lane >> 4;

  const int ldr = lane >> 2;
  const int ldk = (((lane & 3) ^ ((lane >> 3) & 3)) * 8);  // pre-swizzled source chunk
  const unsigned short* ap =
      (const unsigned short*)A + (size_t)(gm + wid * 32 + ldr) * K + ldk;
  const unsigned short* bp =
      (const unsigned short*)Bt +
      (size_t)(gn + ((BN == 128) ? wid * 32 : wid * 16) + ldr) * K + ldk;

  const int nkt = K >> 5;

#define STAGE_T(t, buf)                                                    \
  {                                                                        \
    const unsigned short* a_ = ap + (size_t)(t) * 32;                      \
    g2l16((char*)As[buf] + (wid * 2) * 1024, a_);                          \
    g2l16((char*)As[buf] + (wid * 2 + 1) * 1024, a_ + (size_t)16 * K);     \
    const unsigned short* b_ = bp + (size_t)(t) * 32;                      \
    if (BN == 128) {                                                       \
      g2l16((char*)Bs[buf] + (wid * 2) * 1024, b_);                        \
      g2l16((char*)Bs[buf] + (wid * 2 + 1) * 1024, b_ + (size_t)16 * K);   \
    } else {                                                               \
      g2l16((char*)Bs[buf] + wid * 1024, b_);                              \
    }                                                                      \
  }

  STAGE_T(0, 0);
  STAGE_T(1, 1);

  const int cxa = (kg ^ ((fr >> 1) & 3)) * 8;  // swizzled read chunk (shorts)
  f32x4 acc[MR][4] = {};
  for (int t = 0; t < nkt; ++t) {
    const int buf = t % 3;
    if (t + 2 < nkt) STAGE_T(t + 2, (t + 2) % 3);
    const int rem = nkt - 1 - t;
    if (rem >= 2) {
      if (BN == 128) asm volatile("s_waitcnt vmcnt(8)" ::: "memory");
      else           asm volatile("s_waitcnt vmcnt(6)" ::: "memory");
    } else if (rem == 1) {
      if (BN == 128) asm volatile("s_waitcnt vmcnt(4)" ::: "memory");
      else           asm volatile("s_waitcnt vmcnt(3)" ::: "memory");
    } else {
      asm volatile("s_waitcnt vmcnt(0)" ::: "memory");
    }
    __builtin_amdgcn_s_barrier();
    __builtin_amdgcn_sched_barrier(0);
    s16x8 af[MR], bfr[4];
#pragma unroll
    for (int m = 0; m < MR; ++m)
      af[m] = *reinterpret_cast<const s16x8*>(
          &As[buf][(wm * (16 * MR) + m * 16 + fr) * 32 + cxa]);
#pragma unroll
    for (int n = 0; n < 4; ++n)
      bfr[n] = *reinterpret_cast<const s16x8*>(
          &Bs[buf][(wn * 64 + n * 16 + fr) * 32 + cxa]);
#pragma unroll
    for (int m = 0; m < MR; ++m)
#pragma unroll
      for (int n = 0; n < 4; ++n)
        acc[m][n] = __builtin_amdgcn_mfma_f32_16x16x32_bf16(af[m], bfr[n], acc[m][n], 0, 0, 0);
    __builtin_amdgcn_sched_barrier(0);
    __builtin_amdgcn_s_barrier();
  }
#undef STAGE_T

  const int r0 = gm + wm * (16 * MR);
  const int c0 = gn + wn * 64;
  float bb[4];
#pragma unroll
  for (int n = 0; n < 4; ++n)
    bb[n] = bias ? bias[c0 + n * 16 + fr] : 0.0f;
#pragma unroll
  for (int m = 0; m < MR; ++m) {
#pragma unroll
    for (int j = 0; j < 4; ++j) {
      const int row = r0 + m * 16 + kg * 4 + j;
#pragma unroll
      for (int n = 0; n < 4; ++n) {
        float val = acc[m][n][j] + bb[n];
        const size_t idx = (size_t)row * N + c0 + n * 16 + fr;
        if (MODE == 0) {
          ((unsigned short*)Cout)[idx] = f2b(val);
        } else if (MODE == 1) {
          float* cp = (float*)Cout + idx;
          *cp = *cp + val;
        } else {
          ((unsigned short*)Cout)[idx] = f2b(gelu_f(val));
        }
      }
    }
  }
}

// ---------------- split-K=2 GEMM (BN=64): z=0 -> x += bias + acc; z=1 -> partial ----
__global__ __launch_bounds__(256) void gemm_sk2(
    const __hip_bfloat16* __restrict__ A,
    const __hip_bfloat16* __restrict__ Bt,
    const float* __restrict__ bias,
    float* __restrict__ X, float* __restrict__ P,
    int N, int K /* full stride */, int KS /* per-split extent */) {
  __shared__ short As[3][128 * 32];
  __shared__ short Bs[3][64 * 32];
  int bid = blockIdx.y * gridDim.x + blockIdx.x;
  const int nwg = gridDim.x * gridDim.y;
  bid = (bid & 7) * (nwg >> 3) + (bid >> 3);
  const int gn = (bid % gridDim.x) * 64;
  const int gm = (bid / gridDim.x) * 128;
  const int koff = blockIdx.z * KS;

  const int tid = threadIdx.x;
  const int wid = tid >> 6, lane = tid & 63;
  const int wm = wid, wn = 0;
  const int fr = lane & 15, kg = lane >> 4;

  const int ldr = lane >> 2;
  const int ldk = (((lane & 3) ^ ((lane >> 3) & 3)) * 8);
  const unsigned short* ap =
      (const unsigned short*)A + (size_t)(gm + wid * 32 + ldr) * K + koff + ldk;
  const unsigned short* bp =
      (const unsigned short*)Bt + (size_t)(gn + wid * 16 + ldr) * K + koff + ldk;

  const int nkt = KS >> 5;

#define STAGE_S(t, buf)                                                    \
  {                                                                        \
    const unsigned short* a_ = ap + (size_t)(t) * 32;                      \
    g2l16((char*)As[buf] + (wid * 2) * 1024, a_);                          \
    g2l16((char*)As[buf] + (wid * 2 + 1) * 1024, a_ + (size_t)16 * K);     \
    g2l16((char*)Bs[buf] + wid * 1024, bp + (size_t)(t) * 32);             \
  }

  STAGE_S(0, 0);
  STAGE_S(1, 1);

  const int cxa = (kg ^ ((fr >> 1) & 3)) * 8;
  f32x4 acc[2][4] = {};
  for (int t = 0; t < nkt; ++t) {
    const int buf = t % 3;
    if (t + 2 < nkt) STAGE_S(t + 2, (t + 2) % 3);
    const int rem = nkt - 1 - t;
    if (rem >= 2)      asm volatile("s_waitcnt vmcnt(6)" ::: "memory");
    else if (rem == 1) asm volatile("s_waitcnt vmcnt(3)" ::: "memory");
    else               asm volatile("s_waitcnt vmcnt(0)" ::: "memory");
    __builtin_amdgcn_s_barrier();
    __builtin_amdgcn_sched_barrier(0);
    s16x8 af[2], bfr[4];
#pragma unroll
    for (int m = 0; m < 2; ++m)
      af[m] = *reinterpret_cast<const s16x8*>(
          &As[buf][(wm * 32 + m * 16 + fr) * 32 + cxa]);
#pragma unroll
    for (int n = 0; n < 4; ++n)
      bfr[n] = *reinterpret_cast<const s16x8*>(
          &Bs[buf][(wn * 64 + n * 16 + fr) * 32 + cxa]);
#pragma unroll
    for (int m = 0; m < 2; ++m)
#pragma unroll
      for (int n = 0; n < 4; ++n)
        acc[m][n] = __builtin_amdgcn_mfma_f32_16x16x32_bf16(af[m], bfr[n], acc[m][n], 0, 0, 0);
    __builtin_amdgcn_sched_barrier(0);
    __builtin_amdgcn_s_barrier();
  }
#undef STAGE_S

  const int r0 = gm + wm * 32;
  const int c0 = gn;
  if (blockIdx.z == 0) {
    float bb[4];
#pragma unroll
    for (int n = 0; n < 4; ++n) bb[n] = bias[c0 + n * 16 + fr];
#pragma unroll
    for (int m = 0; m < 2; ++m)
#pragma unroll
      for (int j = 0; j < 4; ++j) {
        const int row = r0 + m * 16 + kg * 4 + j;
#pragma unroll
        for (int n = 0; n < 4; ++n) {
          const size_t idx = (size_t)row * N + c0 + n * 16 + fr;
          X[idx] = X[idx] + acc[m][n][j] + bb[n];
        }
      }
  } else {
#pragma unroll
    for (int m = 0; m < 2; ++m)
#pragma unroll
      for (int j = 0; j < 4; ++j) {
        const int row = r0 + m * 16 + kg * 4 + j;
#pragma unroll
        for (int n = 0; n < 4; ++n) {
          const size_t idx = (size_t)row * N + c0 + n * 16 + fr;
          P[idx] = acc[m][n][j];
        }
      }
  }
}

// ---------------- MFMA flash attention v3: QBLK=128 (unchanged, R6-proven) ----------------
__global__ __launch_bounds__(256) void attn_mfma(
    const __hip_bfloat16* __restrict__ qkv, __hip_bfloat16* __restrict__ yg) {
  const int qb = 7 - blockIdx.x;  // heavy first
  const int hh = blockIdx.y;
  const int bb = blockIdx.z;
  __shared__ short Qs[128 * 64];  // Q staging, then P
  __shared__ short Ks[64 * 64];
  __shared__ short Vt[64 * 64];   // V transposed: row=d, col=k (swizzled)
  const int tid = threadIdx.x;
  const int wid = tid >> 6, lane = tid & 63;
  const int fr = lane & 15, kg = lane >> 4;
  const size_t qb_base = (size_t)bb * T_ * QSTR_ + (size_t)hh * DH_;
  const unsigned short* qgp = (const unsigned short*)qkv + qb_base;
  const unsigned short* kgp = qgp + 1024;
  const unsigned short* vgp = qgp + 2048;
  const float C = 0.125f * 1.4426950408889634f;  // scale * log2(e)

  {
    const int r8 = lane >> 3, cp = lane & 7;
#pragma unroll
    for (int u = 0; u < 4; ++u) {
      const int row = wid * 32 + u * 8 + r8;
      const int c16 = cp ^ (row & 7);
      g2l16((char*)Qs + (wid * 32 + u * 8) * 128,
            qgp + (size_t)(qb * 128 + row) * QSTR_ + c16 * 8);
    }
  }
  asm volatile("s_waitcnt vmcnt(0)" ::: "memory");
  __syncthreads();
  s16x8 qf[2][2];
#pragma unroll
  for (int rg = 0; rg < 2; ++rg) {
    const int row = wid * 32 + rg * 16 + fr;
    const char* rp = (const char*)Qs + row * 128;
    qf[rg][0] = *reinterpret_cast<const s16x8*>(rp + (((0 + kg) ^ (row & 7)) << 4));
    qf[rg][1] = *reinterpret_cast<const s16x8*>(rp + (((4 + kg) ^ (row & 7)) << 4));
  }

  f32x4 acco[2][4] = {};
  float m_run[2][4], l_run[2][4];
#pragma unroll
  for (int rg = 0; rg < 2; ++rg)
#pragma unroll
    for (int j = 0; j < 4; ++j) { m_run[rg][j] = -INFINITY; l_run[rg][j] = 0.f; }

  const int q16hi = qb * 8 + wid * 2 + 1;
  const int ntile = 2 * qb + 2;
  for (int kt = 0; kt < ntile; ++kt) {
    __syncthreads();
    {
      const int r8 = lane >> 3, cp = lane & 7;
#pragma unroll
      for (int u = 0; u < 2; ++u) {
        const int row = wid * 16 + u * 8 + r8;
        const int c16 = cp ^ (row & 7);
        g2l16((char*)Ks + (wid * 16 + u * 8) * 128,
              kgp + (size_t)(kt * 64 + row) * QSTR_ + c16 * 8);
      }
    }
    {
      const int kv0 = tid >> 3;
      const int d0 = (tid & 7) * 8;
      const int rot = tid & 7;
#pragma unroll
      for (int u = 0; u < 2; ++u) {
        const int kv = u * 32 + kv0;
        s16x8 sv = *reinterpret_cast<const s16x8*>(
            vgp + (size_t)(kt * 64 + kv) * QSTR_ + d0);
#pragma unroll
        for (int j = 0; j < 8; ++j) {
          const int jj = (j + rot) & 7;
          const int d = d0 + jj;
          *(short*)((char*)Vt + d * 128 + ((((kv >> 3) ^ jj) & 7) << 4) + (kv & 7) * 2) = sv[jj];
        }
      }
    }
    asm volatile("s_waitcnt vmcnt(0)" ::: "memory");
    __syncthreads();

    if (kt * 4 <= q16hi) {
      f32x4 accs[2][4] = {};
#pragma unroll
      for (int n = 0; n < 4; ++n) {
        const int row = n * 16 + fr;
        const char* rp = (const char*)Ks + row * 128;
        s16x8 kf0 = *reinterpret_cast<const s16x8*>(rp + (((0 + kg) ^ (row & 7)) << 4));
        s16x8 kf1 = *reinterpret_cast<const s16x8*>(rp + (((4 + kg) ^ (row & 7)) << 4));
#pragma unroll
        for (int rg = 0; rg < 2; ++rg) {
          accs[rg][n] = __builtin_amdgcn_mfma_f32_16x16x32_bf16(qf[rg][0], kf0, accs[rg][n], 0, 0, 0);
          accs[rg][n] = __builtin_amdgcn_mfma_f32_16x16x32_bf16(qf[rg][1], kf1, accs[rg][n], 0, 0, 0);
        }
      }
#pragma unroll
      for (int rg = 0; rg < 2; ++rg) {
        const int q16 = qb * 8 + wid * 2 + rg;
        float mloc[4] = {-3.0e38f, -3.0e38f, -3.0e38f, -3.0e38f};
#pragma unroll
        for (int n = 0; n < 4; ++n)
          if (kt * 4 + n <= q16)
#pragma unroll
            for (int j = 0; j < 4; ++j) mloc[j] = fmaxf(mloc[j], accs[rg][n][j]);
#pragma unroll
        for (int off = 1; off < 16; off <<= 1)
#pragma unroll
          for (int j = 0; j < 4; ++j) mloc[j] = fmaxf(mloc[j], __shfl_xor(mloc[j], off));
        float a_[4];
#pragma unroll
        for (int j = 0; j < 4; ++j) {
          const float mn = fmaxf(m_run[rg][j], mloc[j]);
          a_[j] = EXP2F((m_run[rg][j] - mn) * C);
          m_run[rg][j] = mn;
        }
        float psum[4] = {};
#pragma unroll
        for (int n = 0; n < 4; ++n) {
          const bool dead = (kt * 4 + n > q16);
          const int c16b = n * 2 + (fr >> 3);
#pragma unroll
          for (int j = 0; j < 4; ++j) {
            float p = dead ? 0.0f : EXP2F((accs[rg][n][j] - m_run[rg][j]) * C);
            psum[j] += p;
            const int row = wid * 32 + rg * 16 + kg * 4 + j;
            *(short*)((char*)Qs + row * 128 + (((c16b ^ (row & 7)) & 7) << 4) + (fr & 7) * 2) =
                (short)f2b(p);
          }
        }
#pragma unroll
        for (int j = 0; j < 4; ++j) l_run[rg][j] = l_run[rg][j] * a_[j] + psum[j];
#pragma unroll
        for (int dt = 0; dt < 4; ++dt)
#pragma unroll
          for (int j = 0; j < 4; ++j) acco[rg][dt][j] *= a_[j];
      }
#pragma unroll
      for (int rg = 0; rg < 2; ++rg) {
        const int prow = wid * 32 + rg * 16 + fr;
        const char* pp = (const char*)Qs + prow * 128;
#pragma unroll
        for (int kk = 0; kk < 2; ++kk) {
          const s16x8 pf = *reinterpret_cast<const s16x8*>(
              pp + ((((kk * 4 + kg) ^ (prow & 7)) & 7) << 4));
#pragma unroll
          for (int dt = 0; dt < 4; ++dt) {
            const int vrow = dt * 16 + fr;
            const s16x8 vf = *reinterpret_cast<const s16x8*>(
                (const char*)Vt + vrow * 128 + ((((kk * 4 + kg) ^ (vrow & 7)) & 7) << 4));
            acco[rg][dt] = __builtin_amdgcn_mfma_f32_16x16x32_bf16(pf, vf, acco[rg][dt], 0, 0, 0);
          }
        }
      }
    }
  }

#pragma unroll
  for (int off = 1; off < 16; off <<= 1)
#pragma unroll
    for (int rg = 0; rg < 2; ++rg)
#pragma unroll
      for (int j = 0; j < 4; ++j) l_run[rg][j] += __shfl_xor(l_run[rg][j], off);
  unsigned short* yp = (unsigned short*)yg + (size_t)bb * T_ * D_ + (size_t)hh * DH_;
#pragma unroll
  for (int rg = 0; rg < 2; ++rg) {
    float inv[4];
#pragma unroll
    for (int j = 0; j < 4; ++j) inv[j] = 1.0f / l_run[rg][j];
#pragma unroll
    for (int dt = 0; dt < 4; ++dt)
#pragma unroll
      for (int j = 0; j < 4; ++j) {
        const int row = qb * 128 + wid * 32 + rg * 16 + kg * 4 + j;
        yp[(size_t)row * D_ + dt * 16 + fr] = f2b(acco[rg][dt][j] * inv[j]);
      }
  }
}

extern "C" void kernel_launch(void* const* d_in, const int* in_sizes, int n_in,
                              void* d_out, int out_size, void* d_ws, size_t ws_size,
                              hipStream_t stream) {
  (void)in_sizes; (void)n_in; (void)out_size; (void)ws_size;
  const float* seq  = (const float*)d_in[0];
  const float* Wq   = (const float*)d_in[1];
  const float* bq   = (const float*)d_in[2];
  const float* Wk   = (const float*)d_in[3];
  const float* bk   = (const float*)d_in[4];
  const float* Wv   = (const float*)d_in[5];
  const float* bv   = (const float*)d_in[6];
  const float* Wp   = (const float*)d_in[7];
  const float* bp   = (const float*)d_in[8];
  const float* ln1g = (const float*)d_in[9];
  const float* ln1b = (const float*)d_in[10];
  const float* ln2g = (const float*)d_in[11];
  const float* ln2b = (const float*)d_in[12];
  const float* W1   = (const float*)d_in[13];
  const float* b1   = (const float*)d_in[14];
  const float* W2   = (const float*)d_in[15];
  const float* b2   = (const float*)d_in[16];
  const float* lnfg = (const float*)d_in[17];
  const float* lnfb = (const float*)d_in[18];

  float* x = (float*)d_out;
  char* ws = (char*)d_ws;
  const size_t MB = 1024ull * 1024ull;
  typedef __hip_bfloat16 bf16;
  bf16*  wtqkv = (bf16*)(ws + 0 * MB);    // [3072][1024]
  bf16*  wtp   = (bf16*)(ws + 6 * MB);    // [1024][1024]
  bf16*  wtF1  = (bf16*)(ws + 8 * MB);    // [4096][1024]
  bf16*  wtF2  = (bf16*)(ws + 16 * MB);   // [1024][4096]
  bf16*  hb    = (bf16*)(ws + 24 * MB);   // [4096][1024]
  bf16*  qkv   = (bf16*)(ws + 32 * MB);   // [4096][3072]
  bf16*  mid   = (bf16*)(ws + 56 * MB);   // [4096][4096]
  float* bqkv  = (float*)(ws + 88 * MB);  // [8][3072]
  float* part  = (float*)(ws + 32 * MB);  // 16MB split-K partial; qkv region is
                                          // dead during FFN (attn already consumed it)

  hipMemcpyAsync(x, seq, (size_t)M_ * D_ * sizeof(float), hipMemcpyDeviceToDevice, stream);

  const dim3 blk(256);
  concat_bias<<<96, blk, 0, stream>>>(bq, bk, bv, bqkv);

  for (int i = 0; i < 8; ++i) {
    const size_t wo  = (size_t)i * D_ * D_;
    const size_t vo  = (size_t)i * D_;
    const size_t w1o = (size_t)i * D_ * 4 * D_;

    ln_kernel<true><<<M_, blk, 0, stream>>>(x, hb, ln1g + vo, ln1b + vo);
    TrAll ta;
    ta.wq = Wq + wo; ta.wk = Wk + wo; ta.wv = Wv + wo; ta.wp = Wp + wo;
    ta.w1 = W1 + w1o; ta.w2 = W2 + w1o;
    ta.dqkv = wtqkv; ta.dp = wtp; ta.d1 = wtF1; ta.d2 = wtF2;
    transpose_all<<<12288, blk, 0, stream>>>(ta);
    gemm_mfma<0, 128><<<dim3(24, 32), blk, 0, stream>>>(
        hb, wtqkv, bqkv + (size_t)i * QSTR_, qkv, QSTR_, 1024);
    attn_mfma<<<dim3(8, 16, 4), blk, 0, stream>>>(qkv, hb);
    gemm_mfma<1, 64><<<dim3(16, 32), blk, 0, stream>>>(hb, wtp, bp + vo, x, 1024, 1024);
    ln_kernel<true><<<M_, blk, 0, stream>>>(x, hb, ln2g + vo, ln2b + vo);
    gemm_mfma<2, 128><<<dim3(32, 32), blk, 0, stream>>>(
        hb, wtF1, b1 + (size_t)i * 4096, mid, 4096, 1024);
    // FFN down with deterministic split-K=2: 1024 blocks -> 4/CU
    gemm_sk2<<<dim3(16, 32, 2), blk, 0, stream>>>(
        mid, wtF2, b2 + vo, x, part, 1024, 4096, 2048);
    reduce_add<<<4096, blk, 0, stream>>>(x, part);
  }
  ln_kernel<false><<<M_, blk, 0, stream>>>(x, x, lnfg, lnfb);
}

// Round 10
// 2171.057 us; speedup vs baseline: 1.0705x; 1.0321x over previous
//
#include <hip/hip_runtime.h>
#include <hip/hip_bf16.h>
#include <math.h>

#define B_ 4
#define T_ 1024
#define D_ 1024
#define H_ 16
#define DH_ 64
#define M_ 4096
#define QSTR_ 3072   // fused qkv row stride
#define EPS_ 1e-5f

typedef __attribute__((ext_vector_type(4))) float f32x4;
typedef __attribute__((ext_vector_type(8))) short s16x8;

#if __has_builtin(__builtin_amdgcn_exp2f)
#define EXP2F __builtin_amdgcn_exp2f
#else
#define EXP2F exp2f
#endif

__device__ __forceinline__ float gelu_f(float x) {
  return 0.5f * x * (1.0f + erff(x * 0.70710678118654752f));
}
__device__ __forceinline__ float b2f(unsigned short u) {
  union { unsigned int i; float f; } c; c.i = ((unsigned int)u) << 16; return c.f;
}
__device__ __forceinline__ unsigned short f2b(float f) {
  __hip_bfloat16 h = __float2bfloat16(f);
  return *reinterpret_cast<unsigned short*>(&h);
}
__device__ __forceinline__ void g2l16(void* l, const void* g) {
  __builtin_amdgcn_global_load_lds(
      (const __attribute__((address_space(1))) void*)g,
      (__attribute__((address_space(3))) void*)l, 16, 0, 0);
}

// ---------------- LayerNorm ----------------
template<bool BF16OUT>
__global__ __launch_bounds__(256) void ln_kernel(
    const float* __restrict__ in, void* __restrict__ out,
    const float* __restrict__ g, const float* __restrict__ b) {
  const int row = blockIdx.x;
  const int tid = threadIdx.x;
  const float* rp = in + (size_t)row * D_;
  float4 v = *reinterpret_cast<const float4*>(rp + tid * 4);
  float s = v.x + v.y + v.z + v.w;
  float s2 = v.x * v.x + v.y * v.y + v.z * v.z + v.w * v.w;
#pragma unroll
  for (int off = 1; off < 64; off <<= 1) {
    s += __shfl_xor(s, off);
    s2 += __shfl_xor(s2, off);
  }
  __shared__ float red[2][4];
  const int wid = tid >> 6;
  if ((tid & 63) == 0) { red[0][wid] = s; red[1][wid] = s2; }
  __syncthreads();
  s = red[0][0] + red[0][1] + red[0][2] + red[0][3];
  s2 = red[1][0] + red[1][1] + red[1][2] + red[1][3];
  const float mu = s * (1.0f / D_);
  const float var = s2 * (1.0f / D_) - mu * mu;
  const float rs = rsqrtf(var + EPS_);
  float4 gv = *reinterpret_cast<const float4*>(g + tid * 4);
  float4 bv = *reinterpret_cast<const float4*>(b + tid * 4);
  float o0 = (v.x - mu) * rs * gv.x + bv.x;
  float o1 = (v.y - mu) * rs * gv.y + bv.y;
  float o2 = (v.z - mu) * rs * gv.z + bv.z;
  float o3 = (v.w - mu) * rs * gv.w + bv.w;
  if (BF16OUT) {
    ushort4 pk;
    pk.x = f2b(o0); pk.y = f2b(o1); pk.z = f2b(o2); pk.w = f2b(o3);
    *reinterpret_cast<ushort4*>((unsigned short*)out + (size_t)row * D_ + tid * 4) = pk;
  } else {
    *reinterpret_cast<float4*>((float*)out + (size_t)row * D_ + tid * 4) =
        make_float4(o0, o1, o2, o3);
  }
}

// ---------------- bias concat: [L][3072] <- bq|bk|bv ----------------
__global__ __launch_bounds__(256) void concat_bias(
    const float* __restrict__ bq, const float* __restrict__ bk,
    const float* __restrict__ bv, float* __restrict__ out) {
  const int i = blockIdx.x * 256 + threadIdx.x;
  const int l = i / QSTR_, c = i % QSTR_;
  const float* src = (c < 1024) ? bq : ((c < 2048) ? bk : bv);
  out[i] = src[l * 1024 + (c & 1023)];
}

// ---------------- x += partial (split-K reduction, deterministic) ----------------
__global__ __launch_bounds__(256) void reduce_add(
    float* __restrict__ x, const float* __restrict__ p) {
  const int i = blockIdx.x * 256 + threadIdx.x;
  float4 a = reinterpret_cast<float4*>(x)[i];
  float4 b = reinterpret_cast<const float4*>(p)[i];
  a.x += b.x; a.y += b.y; a.z += b.z; a.w += b.w;
  reinterpret_cast<float4*>(x)[i] = a;
}

// ---------------- all weight transposes for one layer, single launch ----------------
__device__ __forceinline__ void transpose_tile(
    const float* __restrict__ src, int sld,
    __hip_bfloat16* __restrict__ dst, int dld, int k0, int n0) {
  __shared__ float tile[32][33];
  const int t = threadIdx.x;
  const int r = t >> 3;
  const int cq = (t & 7) * 4;
  float4 vv = *reinterpret_cast<const float4*>(src + (size_t)(k0 + r) * sld + n0 + cq);
  tile[r][cq + 0] = vv.x; tile[r][cq + 1] = vv.y;
  tile[r][cq + 2] = vv.z; tile[r][cq + 3] = vv.w;
  __syncthreads();
  ushort4 o;
  o.x = f2b(tile[cq + 0][r]); o.y = f2b(tile[cq + 1][r]);
  o.z = f2b(tile[cq + 2][r]); o.w = f2b(tile[cq + 3][r]);
  *reinterpret_cast<ushort4*>((unsigned short*)dst + (size_t)(n0 + r) * dld + k0 + cq) = o;
}

struct TrAll {
  const float *wq, *wk, *wv, *wp, *w1, *w2;
  __hip_bfloat16 *dqkv, *dp, *d1, *d2;
};

__global__ __launch_bounds__(256) void transpose_all(TrAll a) {
  const int t = blockIdx.x;
  const float* src;
  __hip_bfloat16* dst;
  int sld, dld, k0, n0;
  if (t < 4096) {
    const int m = t >> 10, tile = t & 1023;
    k0 = (tile >> 5) * 32; n0 = (tile & 31) * 32;
    src = (m == 0) ? a.wq : (m == 1) ? a.wk : (m == 2) ? a.wv : a.wp;
    sld = 1024; dld = 1024;
    dst = (m < 3) ? (a.dqkv + (size_t)m * 1024 * 1024) : a.dp;
  } else if (t < 8192) {
    const int tile = t - 4096;
    k0 = (tile & 31) * 32; n0 = (tile >> 5) * 32;
    src = a.w1; sld = 4096; dst = a.d1; dld = 1024;
  } else {
    const int tile = t - 8192;
    k0 = (tile >> 5) * 32; n0 = (tile & 31) * 32;
    src = a.w2; sld = 1024; dst = a.d2; dld = 4096;
  }
  transpose_tile(src, sld, dst, dld, k0, n0);
}

// ---------------- bf16 MFMA GEMM 128xBN (4 waves): 3-deep pipeline + swizzle ----
// MODE 0: store bf16; MODE 1: fp32 C += result; MODE 2: store bf16 gelu(result)
template<int MODE, int BN>
__global__ __launch_bounds__(256) void gemm_mfma(
    const __hip_bfloat16* __restrict__ A,
    const __hip_bfloat16* __restrict__ Bt,
    const float* __restrict__ bias,
    void* __restrict__ Cout, int N, int K) {
  __shared__ short As[3][128 * 32];
  __shared__ short Bs[3][BN * 32];
  int bid = blockIdx.y * gridDim.x + blockIdx.x;
  const int nwg = gridDim.x * gridDim.y;
  bid = (bid & 7) * (nwg >> 3) + (bid >> 3);
  const int gn = (bid % gridDim.x) * BN;
  const int gm = (bid / gridDim.x) * 128;

  const int tid = threadIdx.x;
  const int wid = tid >> 6, lane = tid & 63;
  constexpr int MR = (BN == 128) ? 4 : 2;
  const int wm = (BN == 128) ? (wid >> 1) : wid;
  const int wn = (BN == 128) ? (wid & 1) : 0;
  const int fr = lane & 15, kg = lane >> 4;

  const int ldr = lane >> 2;
  const int ldk = (((lane & 3) ^ ((lane >> 3) & 3)) * 8);  // pre-swizzled source chunk
  const unsigned short* ap =
      (const unsigned short*)A + (size_t)(gm + wid * 32 + ldr) * K + ldk;
  const unsigned short* bp =
      (const unsigned short*)Bt +
      (size_t)(gn + ((BN == 128) ? wid * 32 : wid * 16) + ldr) * K + ldk;

  const int nkt = K >> 5;

#define STAGE_T(t, buf)                                                    \
  {                                                                        \
    const unsigned short* a_ = ap + (size_t)(t) * 32;                      \
    g2l16((char*)As[buf] + (wid * 2) * 1024, a_);                          \
    g2l16((char*)As[buf] + (wid * 2 + 1) * 1024, a_ + (size_t)16 * K);     \
    const unsigned short* b_ = bp + (size_t)(t) * 32;                      \
    if (BN == 128) {                                                       \
      g2l16((char*)Bs[buf] + (wid * 2) * 1024, b_);                        \
      g2l16((char*)Bs[buf] + (wid * 2 + 1) * 1024, b_ + (size_t)16 * K);   \
    } else {                                                               \
      g2l16((char*)Bs[buf] + wid * 1024, b_);                              \
    }                                                                      \
  }

  STAGE_T(0, 0);
  STAGE_T(1, 1);

  const int cxa = (kg ^ ((fr >> 1) & 3)) * 8;  // swizzled read chunk (shorts)
  f32x4 acc[MR][4] = {};
  for (int t = 0; t < nkt; ++t) {
    const int buf = t % 3;
    if (t + 2 < nkt) STAGE_T(t + 2, (t + 2) % 3);
    const int rem = nkt - 1 - t;
    if (rem >= 2) {
      if (BN == 128) asm volatile("s_waitcnt vmcnt(8)" ::: "memory");
      else           asm volatile("s_waitcnt vmcnt(6)" ::: "memory");
    } else if (rem == 1) {
      if (BN == 128) asm volatile("s_waitcnt vmcnt(4)" ::: "memory");
      else           asm volatile("s_waitcnt vmcnt(3)" ::: "memory");
    } else {
      asm volatile("s_waitcnt vmcnt(0)" ::: "memory");
    }
    __builtin_amdgcn_s_barrier();
    __builtin_amdgcn_sched_barrier(0);
    s16x8 af[MR], bfr[4];
#pragma unroll
    for (int m = 0; m < MR; ++m)
      af[m] = *reinterpret_cast<const s16x8*>(
          &As[buf][(wm * (16 * MR) + m * 16 + fr) * 32 + cxa]);
#pragma unroll
    for (int n = 0; n < 4; ++n)
      bfr[n] = *reinterpret_cast<const s16x8*>(
          &Bs[buf][(wn * 64 + n * 16 + fr) * 32 + cxa]);
#pragma unroll
    for (int m = 0; m < MR; ++m)
#pragma unroll
      for (int n = 0; n < 4; ++n)
        acc[m][n] = __builtin_amdgcn_mfma_f32_16x16x32_bf16(af[m], bfr[n], acc[m][n], 0, 0, 0);
    __builtin_amdgcn_sched_barrier(0);
    __builtin_amdgcn_s_barrier();
  }
#undef STAGE_T

  const int r0 = gm + wm * (16 * MR);
  const int c0 = gn + wn * 64;
  float bb[4];
#pragma unroll
  for (int n = 0; n < 4; ++n)
    bb[n] = bias ? bias[c0 + n * 16 + fr] : 0.0f;
#pragma unroll
  for (int m = 0; m < MR; ++m) {
#pragma unroll
    for (int j = 0; j < 4; ++j) {
      const int row = r0 + m * 16 + kg * 4 + j;
#pragma unroll
      for (int n = 0; n < 4; ++n) {
        float val = acc[m][n][j] + bb[n];
        const size_t idx = (size_t)row * N + c0 + n * 16 + fr;
        if (MODE == 0) {
          ((unsigned short*)Cout)[idx] = f2b(val);
        } else if (MODE == 1) {
          float* cp = (float*)Cout + idx;
          *cp = *cp + val;
        } else {
          ((unsigned short*)Cout)[idx] = f2b(gelu_f(val));
        }
      }
    }
  }
}

// ------- 128x256 wide GEMM (8 waves, 512 thr): halves B-side cache traffic -------
// Wave grid 2 (rows) x 4 (cols); each wave owns 64x64 — inner loop identical to
// the proven MR=4 path. Optional split-K via gridDim.z (SK=1 -> plain).
// MODE: 0 store bf16; 1 fp32 +=; 2 gelu bf16; 3 split-K (z0: X+=acc+bias, z1: P=acc)
template<int MODE>
__global__ __launch_bounds__(512) void gemm_w256(
    const __hip_bfloat16* __restrict__ A,
    const __hip_bfloat16* __restrict__ Bt,
    const float* __restrict__ bias,
    void* __restrict__ Cout, float* __restrict__ P,
    int N, int K, int KS) {
  __shared__ short As[3][128 * 32];
  __shared__ short Bs[3][256 * 32];
  int bid = blockIdx.y * gridDim.x + blockIdx.x;
  const int nwg = gridDim.x * gridDim.y;
  bid = (bid & 7) * (nwg >> 3) + (bid >> 3);
  const int gn = (bid % gridDim.x) * 256;
  const int gm = (bid / gridDim.x) * 128;
  const int koff = (MODE == 3) ? blockIdx.z * KS : 0;

  const int tid = threadIdx.x;
  const int wid = tid >> 6, lane = tid & 63;
  const int wm = wid & 1, wn = wid >> 1;  // 2 x 4 waves of 64x64
  const int fr = lane & 15, kg = lane >> 4;

  const int ldr = lane >> 2;
  const int ldk = (((lane & 3) ^ ((lane >> 3) & 3)) * 8);
  const unsigned short* ap =
      (const unsigned short*)A + (size_t)(gm + wid * 16 + ldr) * K + koff + ldk;
  const unsigned short* bp =
      (const unsigned short*)Bt + (size_t)(gn + wid * 32 + ldr) * K + koff + ldk;

  const int nkt = ((MODE == 3) ? KS : K) >> 5;

#define STAGE_W(t, buf)                                                    \
  {                                                                        \
    g2l16((char*)As[buf] + wid * 1024, ap + (size_t)(t) * 32);             \
    const unsigned short* b_ = bp + (size_t)(t) * 32;                      \
    g2l16((char*)Bs[buf] + (wid * 2) * 1024, b_);                          \
    g2l16((char*)Bs[buf] + (wid * 2 + 1) * 1024, b_ + (size_t)16 * K);     \
  }

  STAGE_W(0, 0);
  STAGE_W(1, 1);

  const int cxa = (kg ^ ((fr >> 1) & 3)) * 8;
  f32x4 acc[4][4] = {};
  for (int t = 0; t < nkt; ++t) {
    const int buf = t % 3;
    if (t + 2 < nkt) STAGE_W(t + 2, (t + 2) % 3);
    const int rem = nkt - 1 - t;
    if (rem >= 2)      asm volatile("s_waitcnt vmcnt(6)" ::: "memory");
    else if (rem == 1) asm volatile("s_waitcnt vmcnt(3)" ::: "memory");
    else               asm volatile("s_waitcnt vmcnt(0)" ::: "memory");
    __builtin_amdgcn_s_barrier();
    __builtin_amdgcn_sched_barrier(0);
    s16x8 af[4], bfr[4];
#pragma unroll
    for (int m = 0; m < 4; ++m)
      af[m] = *reinterpret_cast<const s16x8*>(
          &As[buf][(wm * 64 + m * 16 + fr) * 32 + cxa]);
#pragma unroll
    for (int n = 0; n < 4; ++n)
      bfr[n] = *reinterpret_cast<const s16x8*>(
          &Bs[buf][(wn * 64 + n * 16 + fr) * 32 + cxa]);
#pragma unroll
    for (int m = 0; m < 4; ++m)
#pragma unroll
      for (int n = 0; n < 4; ++n)
        acc[m][n] = __builtin_amdgcn_mfma_f32_16x16x32_bf16(af[m], bfr[n], acc[m][n], 0, 0, 0);
    __builtin_amdgcn_sched_barrier(0);
    __builtin_amdgcn_s_barrier();
  }
#undef STAGE_W

  const int r0 = gm + wm * 64;
  const int c0 = gn + wn * 64;
  if (MODE == 3 && blockIdx.z == 1) {
#pragma unroll
    for (int m = 0; m < 4; ++m)
#pragma unroll
      for (int j = 0; j < 4; ++j) {
        const int row = r0 + m * 16 + kg * 4 + j;
#pragma unroll
        for (int n = 0; n < 4; ++n)
          P[(size_t)row * N + c0 + n * 16 + fr] = acc[m][n][j];
      }
    return;
  }
  float bb[4];
#pragma unroll
  for (int n = 0; n < 4; ++n)
    bb[n] = bias ? bias[c0 + n * 16 + fr] : 0.0f;
#pragma unroll
  for (int m = 0; m < 4; ++m) {
#pragma unroll
    for (int j = 0; j < 4; ++j) {
      const int row = r0 + m * 16 + kg * 4 + j;
#pragma unroll
      for (int n = 0; n < 4; ++n) {
        float val = acc[m][n][j] + bb[n];
        const size_t idx = (size_t)row * N + c0 + n * 16 + fr;
        if (MODE == 0) {
          ((unsigned short*)Cout)[idx] = f2b(val);
        } else if (MODE == 1 || MODE == 3) {
          float* cp = (float*)Cout + idx;
          *cp = *cp + val;
        } else {
          ((unsigned short*)Cout)[idx] = f2b(gelu_f(val));
        }
      }
    }
  }
}

// ---------------- MFMA flash attention v3: QBLK=128 (unchanged, R6-proven) ----------------
__global__ __launch_bounds__(256) void attn_mfma(
    const __hip_bfloat16* __restrict__ qkv, __hip_bfloat16* __restrict__ yg) {
  const int qb = 7 - blockIdx.x;  // heavy first
  const int hh = blockIdx.y;
  const int bb = blockIdx.z;
  __shared__ short Qs[128 * 64];  // Q staging, then P
  __shared__ short Ks[64 * 64];
  __shared__ short Vt[64 * 64];   // V transposed: row=d, col=k (swizzled)
  const int tid = threadIdx.x;
  const int wid = tid >> 6, lane = tid & 63;
  const int fr = lane & 15, kg = lane >> 4;
  const size_t qb_base = (size_t)bb * T_ * QSTR_ + (size_t)hh * DH_;
  const unsigned short* qgp = (const unsigned short*)qkv + qb_base;
  const unsigned short* kgp = qgp + 1024;
  const unsigned short* vgp = qgp + 2048;
  const float C = 0.125f * 1.4426950408889634f;  // scale * log2(e)

  {
    const int r8 = lane >> 3, cp = lane & 7;
#pragma unroll
    for (int u = 0; u < 4; ++u) {
      const int row = wid * 32 + u * 8 + r8;
      const int c16 = cp ^ (row & 7);
      g2l16((char*)Qs + (wid * 32 + u * 8) * 128,
            qgp + (size_t)(qb * 128 + row) * QSTR_ + c16 * 8);
    }
  }
  asm volatile("s_waitcnt vmcnt(0)" ::: "memory");
  __syncthreads();
  s16x8 qf[2][2];
#pragma unroll
  for (int rg = 0; rg < 2; ++rg) {
    const int row = wid * 32 + rg * 16 + fr;
    const char* rp = (const char*)Qs + row * 128;
    qf[rg][0] = *reinterpret_cast<const s16x8*>(rp + (((0 + kg) ^ (row & 7)) << 4));
    qf[rg][1] = *reinterpret_cast<const s16x8*>(rp + (((4 + kg) ^ (row & 7)) << 4));
  }

  f32x4 acco[2][4] = {};
  float m_run[2][4], l_run[2][4];
#pragma unroll
  for (int rg = 0; rg < 2; ++rg)
#pragma unroll
    for (int j = 0; j < 4; ++j) { m_run[rg][j] = -INFINITY; l_run[rg][j] = 0.f; }

  const int q16hi = qb * 8 + wid * 2 + 1;
  const int ntile = 2 * qb + 2;
  for (int kt = 0; kt < ntile; ++kt) {
    __syncthreads();
    {
      const int r8 = lane >> 3, cp = lane & 7;
#pragma unroll
      for (int u = 0; u < 2; ++u) {
        const int row = wid * 16 + u * 8 + r8;
        const int c16 = cp ^ (row & 7);
        g2l16((char*)Ks + (wid * 16 + u * 8) * 128,
              kgp + (size_t)(kt * 64 + row) * QSTR_ + c16 * 8);
      }
    }
    {
      const int kv0 = tid >> 3;
      const int d0 = (tid & 7) * 8;
      const int rot = tid & 7;
#pragma unroll
      for (int u = 0; u < 2; ++u) {
        const int kv = u * 32 + kv0;
        s16x8 sv = *reinterpret_cast<const s16x8*>(
            vgp + (size_t)(kt * 64 + kv) * QSTR_ + d0);
#pragma unroll
        for (int j = 0; j < 8; ++j) {
          const int jj = (j + rot) & 7;
          const int d = d0 + jj;
          *(short*)((char*)Vt + d * 128 + ((((kv >> 3) ^ jj) & 7) << 4) + (kv & 7) * 2) = sv[jj];
        }
      }
    }
    asm volatile("s_waitcnt vmcnt(0)" ::: "memory");
    __syncthreads();

    if (kt * 4 <= q16hi) {
      f32x4 accs[2][4] = {};
#pragma unroll
      for (int n = 0; n < 4; ++n) {
        const int row = n * 16 + fr;
        const char* rp = (const char*)Ks + row * 128;
        s16x8 kf0 = *reinterpret_cast<const s16x8*>(rp + (((0 + kg) ^ (row & 7)) << 4));
        s16x8 kf1 = *reinterpret_cast<const s16x8*>(rp + (((4 + kg) ^ (row & 7)) << 4));
#pragma unroll
        for (int rg = 0; rg < 2; ++rg) {
          accs[rg][n] = __builtin_amdgcn_mfma_f32_16x16x32_bf16(qf[rg][0], kf0, accs[rg][n], 0, 0, 0);
          accs[rg][n] = __builtin_amdgcn_mfma_f32_16x16x32_bf16(qf[rg][1], kf1, accs[rg][n], 0, 0, 0);
        }
      }
#pragma unroll
      for (int rg = 0; rg < 2; ++rg) {
        const int q16 = qb * 8 + wid * 2 + rg;
        float mloc[4] = {-3.0e38f, -3.0e38f, -3.0e38f, -3.0e38f};
#pragma unroll
        for (int n = 0; n < 4; ++n)
          if (kt * 4 + n <= q16)
#pragma unroll
            for (int j = 0; j < 4; ++j) mloc[j] = fmaxf(mloc[j], accs[rg][n][j]);
#pragma unroll
        for (int off = 1; off < 16; off <<= 1)
#pragma unroll
          for (int j = 0; j < 4; ++j) mloc[j] = fmaxf(mloc[j], __shfl_xor(mloc[j], off));
        float a_[4];
#pragma unroll
        for (int j = 0; j < 4; ++j) {
          const float mn = fmaxf(m_run[rg][j], mloc[j]);
          a_[j] = EXP2F((m_run[rg][j] - mn) * C);
          m_run[rg][j] = mn;
        }
        float psum[4] = {};
#pragma unroll
        for (int n = 0; n < 4; ++n) {
          const bool dead = (kt * 4 + n > q16);
          const int c16b = n * 2 + (fr >> 3);
#pragma unroll
          for (int j = 0; j < 4; ++j) {
            float p = dead ? 0.0f : EXP2F((accs[rg][n][j] - m_run[rg][j]) * C);
            psum[j] += p;
            const int row = wid * 32 + rg * 16 + kg * 4 + j;
            *(short*)((char*)Qs + row * 128 + (((c16b ^ (row & 7)) & 7) << 4) + (fr & 7) * 2) =
                (short)f2b(p);
          }
        }
#pragma unroll
        for (int j = 0; j < 4; ++j) l_run[rg][j] = l_run[rg][j] * a_[j] + psum[j];
#pragma unroll
        for (int dt = 0; dt < 4; ++dt)
#pragma unroll
          for (int j = 0; j < 4; ++j) acco[rg][dt][j] *= a_[j];
      }
#pragma unroll
      for (int rg = 0; rg < 2; ++rg) {
        const int prow = wid * 32 + rg * 16 + fr;
        const char* pp = (const char*)Qs + prow * 128;
#pragma unroll
        for (int kk = 0; kk < 2; ++kk) {
          const s16x8 pf = *reinterpret_cast<const s16x8*>(
              pp + ((((kk * 4 + kg) ^ (prow & 7)) & 7) << 4));
#pragma unroll
          for (int dt = 0; dt < 4; ++dt) {
            const int vrow = dt * 16 + fr;
            const s16x8 vf = *reinterpret_cast<const s16x8*>(
                (const char*)Vt + vrow * 128 + ((((kk * 4 + kg) ^ (vrow & 7)) & 7) << 4));
            acco[rg][dt] = __builtin_amdgcn_mfma_f32_16x16x32_bf16(pf, vf, acco[rg][dt], 0, 0, 0);
          }
        }
      }
    }
  }

#pragma unroll
  for (int off = 1; off < 16; off <<= 1)
#pragma unroll
    for (int rg = 0; rg < 2; ++rg)
#pragma unroll
      for (int j = 0; j < 4; ++j) l_run[rg][j] += __shfl_xor(l_run[rg][j], off);
  unsigned short* yp = (unsigned short*)yg + (size_t)bb * T_ * D_ + (size_t)hh * DH_;
#pragma unroll
  for (int rg = 0; rg < 2; ++rg) {
    float inv[4];
#pragma unroll
    for (int j = 0; j < 4; ++j) inv[j] = 1.0f / l_run[rg][j];
#pragma unroll
    for (int dt = 0; dt < 4; ++dt)
#pragma unroll
      for (int j = 0; j < 4; ++j) {
        const int row = qb * 128 + wid * 32 + rg * 16 + kg * 4 + j;
        yp[(size_t)row * D_ + dt * 16 + fr] = f2b(acco[rg][dt][j] * inv[j]);
      }
  }
}

extern "C" void kernel_launch(void* const* d_in, const int* in_sizes, int n_in,
                              void* d_out, int out_size, void* d_ws, size_t ws_size,
                              hipStream_t stream) {
  (void)in_sizes; (void)n_in; (void)out_size; (void)ws_size;
  const float* seq  = (const float*)d_in[0];
  const float* Wq   = (const float*)d_in[1];
  const float* bq   = (const float*)d_in[2];
  const float* Wk   = (const float*)d_in[3];
  const float* bk   = (const float*)d_in[4];
  const float* Wv   = (const float*)d_in[5];
  const float* bv   = (const float*)d_in[6];
  const float* Wp   = (const float*)d_in[7];
  const float* bp   = (const float*)d_in[8];
  const float* ln1g = (const float*)d_in[9];
  const float* ln1b = (const float*)d_in[10];
  const float* ln2g = (const float*)d_in[11];
  const float* ln2b = (const float*)d_in[12];
  const float* W1   = (const float*)d_in[13];
  const float* b1   = (const float*)d_in[14];
  const float* W2   = (const float*)d_in[15];
  const float* b2   = (const float*)d_in[16];
  const float* lnfg = (const float*)d_in[17];
  const float* lnfb = (const float*)d_in[18];

  float* x = (float*)d_out;
  char* ws = (char*)d_ws;
  const size_t MB = 1024ull * 1024ull;
  typedef __hip_bfloat16 bf16;
  bf16*  wtqkv = (bf16*)(ws + 0 * MB);    // [3072][1024]
  bf16*  wtp   = (bf16*)(ws + 6 * MB);    // [1024][1024]
  bf16*  wtF1  = (bf16*)(ws + 8 * MB);    // [4096][1024]
  bf16*  wtF2  = (bf16*)(ws + 16 * MB);   // [1024][4096]
  bf16*  hb    = (bf16*)(ws + 24 * MB);   // [4096][1024]
  bf16*  qkv   = (bf16*)(ws + 32 * MB);   // [4096][3072]
  bf16*  mid   = (bf16*)(ws + 56 * MB);   // [4096][4096]
  float* bqkv  = (float*)(ws + 88 * MB);  // [8][3072]
  float* part  = (float*)(ws + 32 * MB);  // 16MB split-K partial (qkv dead in FFN)

  hipMemcpyAsync(x, seq, (size_t)M_ * D_ * sizeof(float), hipMemcpyDeviceToDevice, stream);

  const dim3 blk(256);
  const dim3 blkw(512);
  concat_bias<<<96, blk, 0, stream>>>(bq, bk, bv, bqkv);

  for (int i = 0; i < 8; ++i) {
    const size_t wo  = (size_t)i * D_ * D_;
    const size_t vo  = (size_t)i * D_;
    const size_t w1o = (size_t)i * D_ * 4 * D_;

    ln_kernel<true><<<M_, blk, 0, stream>>>(x, hb, ln1g + vo, ln1b + vo);
    TrAll ta;
    ta.wq = Wq + wo; ta.wk = Wk + wo; ta.wv = Wv + wo; ta.wp = Wp + wo;
    ta.w1 = W1 + w1o; ta.w2 = W2 + w1o;
    ta.dqkv = wtqkv; ta.dp = wtp; ta.d1 = wtF1; ta.d2 = wtF2;
    transpose_all<<<12288, blk, 0, stream>>>(ta);
    // fused QKV: 128x256 tiles, grid (12,32) = 384 blocks
    gemm_w256<0><<<dim3(12, 32), blkw, 0, stream>>>(
        hb, wtqkv, bqkv + (size_t)i * QSTR_, qkv, nullptr, QSTR_, 1024, 0);
    attn_mfma<<<dim3(8, 16, 4), blk, 0, stream>>>(qkv, hb);
    gemm_mfma<1, 64><<<dim3(16, 32), blk, 0, stream>>>(hb, wtp, bp + vo, x, 1024, 1024);
    ln_kernel<true><<<M_, blk, 0, stream>>>(x, hb, ln2g + vo, ln2b + vo);
    // FFN up: 128x256 tiles, grid (16,32) = 512 blocks
    gemm_w256<2><<<dim3(16, 32), blkw, 0, stream>>>(
        hb, wtF1, b1 + (size_t)i * 4096, mid, nullptr, 4096, 1024, 0);
    // FFN down: 128x256 split-K=2, grid (4,32,2) = 256 blocks
    gemm_w256<3><<<dim3(4, 32, 2), blkw, 0, stream>>>(
        mid, wtF2, b2 + vo, x, part, 1024, 4096, 2048);
    reduce_add<<<4096, blk, 0, stream>>>(x, part);
  }
  ln_kernel<false><<<M_, blk, 0, stream>>>(x, x, lnfg, lnfb);
}